// Round 15
// baseline (377.575 us; speedup 1.0000x reference)
//
#include <hip/hip_runtime.h>
#include <math.h>

static constexpr int kN   = 50000;
static constexpr int kB   = 500;
static constexpr int kNPG = 100;
static constexpr int kEPG = 1600;
static constexpr int kESG = 800;
static constexpr int kF0  = 128;
static constexpr int kH1  = 256;
static constexpr int kH2  = 128;
#define BN_EPS 1e-5f

typedef _Float16 half8 __attribute__((ext_vector_type(8)));
typedef __attribute__((ext_vector_type(4))) float f32x4;

static constexpr int kCntW = 33;
static constexpr int kAhS  = 136;
static constexpr unsigned kAggLds256 = 45248;   // 3 blocks/CU
static constexpr unsigned kAggLds128 = 80064;   // 2 blocks/CU

// ============ weight prep: W[K][Nc] f32 -> Wt[(kg*Nc + c)*8 + e] fp16 ============
__global__ __launch_bounds__(256)
void wprep_k(const float* __restrict__ s0, const float* __restrict__ s1,
             const float* __restrict__ s2, const float* __restrict__ s3,
             const float* __restrict__ s4, _Float16* __restrict__ d)
{
  int seg = blockIdx.x >> 7;
  int idx = (blockIdx.x & 127) * 256 + threadIdx.x;
  const float* S; int Nc;
  switch (seg) {
    case 0: S = s0; Nc = 256; break;
    case 1: S = s1; Nc = 128; break;
    case 2: S = s2; Nc = 256; break;
    case 3: S = s3; Nc = 128; break;
    default: S = s4; Nc = 256; break;
  }
  int e = idx & 7, t = idx >> 3;
  int c = t % Nc, kg = t / Nc;
  d[seg * 32768 + idx] = (_Float16)S[(size_t)(kg * 8 + e) * Nc + c];
}

// ================= direct-global fp16 MFMA GEMM, 3-wide batched =================
// blockIdx.z in {0..2} selects (A,Wt,C). TRANSM: 0=no transform, 1=always,
// 2=only problem z==0 (block-uniform runtime branch). Wave tile 32x64.
// r14 double-buffer body retained. A-row clamped; stores guarded.
// NOTE: A and C must NOT alias (cross-block race — r2..r4 lesson).
template<int ACT, int TRANSM, int K, int NC, typename AT, typename OT>
__global__ __launch_bounds__(256)
void gemm_direct_k(const AT* __restrict__ A0, const AT* __restrict__ A1, const AT* __restrict__ A2,
                   const _Float16* __restrict__ Wt0, const _Float16* __restrict__ Wt1,
                   const _Float16* __restrict__ Wt2, const float* __restrict__ tr,
                   OT* __restrict__ C0, OT* __restrict__ C1, OT* __restrict__ C2, int M)
{
  constexpr int NK = K / 32;
  const int zb = blockIdx.z;
  const AT* A = (zb == 0) ? A0 : (zb == 1) ? A1 : A2;
  const _Float16* Wt = (zb == 0) ? Wt0 : (zb == 1) ? Wt1 : Wt2;
  OT* C = (zb == 0) ? C0 : (zb == 1) ? C1 : C2;
  const bool doTr = (TRANSM == 1) || (TRANSM == 2 && zb == 0);
  const int tid = threadIdx.x;
  const int lane = tid & 63;
  const int l15 = lane & 15, lg = lane >> 4;
  const int wave = tid >> 6;
  const int wm = wave >> 1, wn = wave & 1;
  const int bm = blockIdx.x * 64;
  const int bn = blockIdx.y * 128;
  f32x4 acc[2][4];
#pragma unroll
  for (int m = 0; m < 2; ++m)
#pragma unroll
    for (int n = 0; n < 4; ++n) acc[m][n] = (f32x4){0.f, 0.f, 0.f, 0.f};

  int arow[2];
#pragma unroll
  for (int m = 0; m < 2; ++m)
    arow[m] = min(bm + wm * 32 + m * 16 + l15, M - 1);
  const int bcol = bn + wn * 64 + l15;

  half8  bBuf[2][4];
  float4 aRF[2][2][2];
  half8  aRH[2][2];

  {
#pragma unroll
    for (int n = 0; n < 4; ++n)
      bBuf[0][n] = *(const half8*)&Wt[((size_t)lg * NC + bcol + n * 16) * 8];
    const int kb = lg * 8;
#pragma unroll
    for (int m = 0; m < 2; ++m) {
      if constexpr (sizeof(AT) == 4) {
        const float* ap = (const float*)A + (size_t)arow[m] * K + kb;
        aRF[0][m][0] = *(const float4*)ap;
        aRF[0][m][1] = *(const float4*)(ap + 4);
      } else {
        aRH[0][m] = *(const half8*)((const _Float16*)A + (size_t)arow[m] * K + kb);
      }
    }
  }

#pragma unroll
  for (int ks = 0; ks < NK; ++ks) {
    const int cur = ks & 1, nxt = cur ^ 1;
    if (ks + 1 < NK) {
      const int kbn = (ks + 1) * 32 + lg * 8;
#pragma unroll
      for (int n = 0; n < 4; ++n)
        bBuf[nxt][n] = *(const half8*)&Wt[((size_t)((ks + 1) * 4 + lg) * NC + bcol + n * 16) * 8];
#pragma unroll
      for (int m = 0; m < 2; ++m) {
        if constexpr (sizeof(AT) == 4) {
          const float* ap = (const float*)A + (size_t)arow[m] * K + kbn;
          aRF[nxt][m][0] = *(const float4*)ap;
          aRF[nxt][m][1] = *(const float4*)(ap + 4);
        } else {
          aRH[nxt][m] = *(const half8*)((const _Float16*)A + (size_t)arow[m] * K + kbn);
        }
      }
    }
    const int kb0 = ks * 32 + lg * 8;
    half8 aF[2];
#pragma unroll
    for (int m = 0; m < 2; ++m) {
      half8 sa;
      if constexpr (sizeof(AT) == 4) {
        float va[8] = {aRF[cur][m][0].x, aRF[cur][m][0].y, aRF[cur][m][0].z, aRF[cur][m][0].w,
                       aRF[cur][m][1].x, aRF[cur][m][1].y, aRF[cur][m][1].z, aRF[cur][m][1].w};
        if (doTr) {
#pragma unroll
          for (int j = 0; j < 8; ++j) va[j] = (va[j] - tr[kb0 + j]) * tr[256 + kb0 + j];
        }
#pragma unroll
        for (int j = 0; j < 8; ++j) sa[j] = (_Float16)va[j];
      } else {
        if (doTr) {
#pragma unroll
          for (int j = 0; j < 8; ++j)
            sa[j] = (_Float16)(((float)aRH[cur][m][j] - tr[kb0 + j]) * tr[256 + kb0 + j]);
        } else {
          sa = aRH[cur][m];
        }
      }
      aF[m] = sa;
    }
#pragma unroll
    for (int m = 0; m < 2; ++m)
#pragma unroll
      for (int n = 0; n < 4; ++n)
        acc[m][n] = __builtin_amdgcn_mfma_f32_16x16x32_f16(aF[m], bBuf[cur][n], acc[m][n], 0, 0, 0);
  }
#pragma unroll
  for (int m = 0; m < 2; ++m) {
    int row_b = bm + wm * 32 + m * 16 + lg * 4;
#pragma unroll
    for (int q = 0; q < 4; ++q) {
      int row = row_b + q;
      if (row >= M) continue;
#pragma unroll
      for (int n = 0; n < 4; ++n) {
        float v = acc[m][n][q];
        if (ACT == 1) v = fmaxf(v, 0.f);
        else if (ACT == 2) v = 1.f / (1.f + expf(-v));
        C[(size_t)row * NC + bn + wn * 64 + n * 16 + l15] = (OT)v;
      }
    }
  }
}

// ======================= small-M tiled f32 GEMM (M<=1000 paths) =======================
template<int ACT>
__global__ __launch_bounds__(256)
void gemm_k(const float* __restrict__ A, const float* __restrict__ W,
            const float* __restrict__ bias, float* __restrict__ C,
            int M, int K, int Nc)
{
  __shared__ float As[32][136];
  __shared__ float Ws[32][68];
  const int tid = threadIdx.x;
  const int bm = blockIdx.x * 128;
  const int bn = blockIdx.y * 64;
  const int tm = (tid & 15) * 8;
  const int tn = (tid >> 4) * 4;
  float acc[8][4];
#pragma unroll
  for (int i = 0; i < 8; ++i)
#pragma unroll
    for (int j = 0; j < 4; ++j) acc[i][j] = 0.f;

  for (int k0 = 0; k0 < K; k0 += 32) {
#pragma unroll
    for (int l = 0; l < 4; ++l) {
      int idx = tid + l * 256;
      int r = idx >> 3;
      int kq = (idx & 7) << 2;
      int gr = bm + r;
      float4 v = make_float4(0.f, 0.f, 0.f, 0.f);
      if (gr < M) v = *(const float4*)&A[(size_t)gr * K + k0 + kq];
      As[kq + 0][r] = v.x; As[kq + 1][r] = v.y;
      As[kq + 2][r] = v.z; As[kq + 3][r] = v.w;
    }
#pragma unroll
    for (int l = 0; l < 2; ++l) {
      int idx = tid + l * 256;
      int r = idx >> 4;
      int nq = (idx & 15) << 2;
      *(float4*)&Ws[r][nq] = *(const float4*)&W[(size_t)(k0 + r) * Nc + bn + nq];
    }
    __syncthreads();
#pragma unroll
    for (int kk = 0; kk < 32; ++kk) {
      float4 a0 = *(float4*)&As[kk][tm];
      float4 a1 = *(float4*)&As[kk][tm + 4];
      float4 w4 = *(float4*)&Ws[kk][tn];
      float am[8] = {a0.x, a0.y, a0.z, a0.w, a1.x, a1.y, a1.z, a1.w};
      float wn4[4] = {w4.x, w4.y, w4.z, w4.w};
#pragma unroll
      for (int i = 0; i < 8; ++i)
#pragma unroll
        for (int j = 0; j < 4; ++j) acc[i][j] += am[i] * wn4[j];
    }
    __syncthreads();
  }
  float4 bv = make_float4(0.f, 0.f, 0.f, 0.f);
  if (bias) bv = *(const float4*)&bias[bn + tn];
#pragma unroll
  for (int i = 0; i < 8; ++i) {
    int row = bm + tm + i;
    if (row >= M) break;
    float o0 = acc[i][0] + bv.x, o1 = acc[i][1] + bv.y;
    float o2 = acc[i][2] + bv.z, o3 = acc[i][3] + bv.w;
    if (ACT == 1) {
      o0 = fmaxf(o0, 0.f); o1 = fmaxf(o1, 0.f);
      o2 = fmaxf(o2, 0.f); o3 = fmaxf(o3, 0.f);
    } else if (ACT == 2) {
      o0 = 1.f / (1.f + expf(-o0)); o1 = 1.f / (1.f + expf(-o1));
      o2 = 1.f / (1.f + expf(-o2)); o3 = 1.f / (1.f + expf(-o3));
    }
    *(float4*)&C[(size_t)row * Nc + bn + tn] = make_float4(o0, o1, o2, o3);
  }
}

// ================= 3-wide per-graph GCN aggregation, MFMA =================
// blockIdx.y in {0,1,2}: 0=main (epg=1600, STATS or MAXP), 1=pos, 2=neg
// (epg=800, SEGBN or POOL). Integer-count adjacency build (deterministic).
// W=256: relu, out fp16; y==0 writes PST column partials, y>0 seg-BN.
// W=128: l2norm; y==0 writes per-node o_z (f32) + z16 (fp16) + col-max
// ZG/ZZ (with noise); y>0 mean-pool to OUT (f32 [B][128]).
template<int W>
__global__ __launch_bounds__(512)
void gcn_agg3_k(const _Float16* __restrict__ H0, const _Float16* __restrict__ H1,
                const _Float16* __restrict__ H2,
                const int* __restrict__ src0, const int* __restrict__ src1,
                const int* __restrict__ src2,
                const int* __restrict__ dst0, const int* __restrict__ dst1,
                const int* __restrict__ dst2,
                const float* __restrict__ bias0, const float* __restrict__ bias12,
                void* __restrict__ OUT0, void* __restrict__ OUT1, void* __restrict__ OUT2,
                const float* __restrict__ NOI, float* __restrict__ PST,
                float* __restrict__ ZG, float* __restrict__ ZZ,
                _Float16* __restrict__ Z16)
{
  extern __shared__ __align__(16) unsigned lds_u[];
  unsigned* cnt32 = lds_u;                                   // [112][33] u32
  _Float16* Adh = (_Float16*)(lds_u + 112 * kCntW);          // [112][136]
  _Float16* Hst = (_Float16*)((char*)lds_u + 45248);         // [128][136] (W=128)
  float* scr = (float*)lds_u;
  __shared__ int scnt[kNPG];
  __shared__ float sdinv[kNPG];
  const int yb = blockIdx.y;
  const _Float16* H = (yb == 0) ? H0 : (yb == 1) ? H1 : H2;
  const int* srcI = (yb == 0) ? src0 : (yb == 1) ? src1 : src2;
  const int* dstI = (yb == 0) ? dst0 : (yb == 1) ? dst1 : dst2;
  const float* bias = (yb == 0) ? bias0 : bias12;
  const int epg = (yb == 0) ? kEPG : kESG;
  const int g = blockIdx.x, tid = threadIdx.x;
  const int base = g * kNPG;
  const size_t ebase = (size_t)g * epg;
  const int lane = tid & 63, wv = tid >> 6;
  const int l15 = lane & 15, lg = lane >> 4;

  for (int i = tid; i < 112 * kCntW; i += 512) cnt32[i] = 0u;
  if constexpr (W == 128) {
    for (int i = tid; i < 128 * 18; i += 512) {
      int c = i / 18, w = i - c * 18;
      ((unsigned*)&Hst[c * kAhS + 100])[w] = 0u;
    }
  }
  if (tid < kNPG) scnt[tid] = 0;
  __syncthreads();
  for (int e = tid; e < epg; e += 512) {
    int s = srcI[ebase + e] - base;
    int d = dstI[ebase + e] - base;
    atomicAdd(&scnt[d], 1);
    atomicAdd(&cnt32[d * kCntW + (s >> 2)], 1u << (8 * (s & 3)));
  }
  __syncthreads();
  if (tid < kNPG) sdinv[tid] = rsqrtf((float)scnt[tid] + 1.f);
  __syncthreads();
  for (int i = tid; i < 112 * kAhS; i += 512) {
    int d = i / kAhS, s = i - d * kAhS;
    float v = 0.f;
    if (d < 100 && s < 100) {
      unsigned w = cnt32[d * kCntW + (s >> 2)];
      unsigned c = (w >> (8 * (s & 3))) & 0xFFu;
      c += (s == d) ? 1u : 0u;
      v = (float)c * sdinv[s] * sdinv[d];
    }
    Adh[i] = (_Float16)v;
  }
  if constexpr (W == 128) {
    const int c = tid & 127;
    for (int j = tid >> 7; j < 100; j += 4)
      Hst[c * kAhS + j] = H[(size_t)(base + j) * 128 + c];
  }
  __syncthreads();

  if constexpr (W == 256) {
    _Float16* OUT = (yb == 0) ? (_Float16*)OUT0 : (yb == 1) ? (_Float16*)OUT1 : (_Float16*)OUT2;
    const int cbase = wv * 32;
    f32x4 acc[7][2];
#pragma unroll
    for (int mt = 0; mt < 7; ++mt) {
      acc[mt][0] = (f32x4){0.f, 0.f, 0.f, 0.f};
      acc[mt][1] = (f32x4){0.f, 0.f, 0.f, 0.f};
    }
#pragma unroll
    for (int k0 = 0; k0 < 128; k0 += 32) {
      const int kb = k0 + lg * 8;
      half8 bF[2];
#pragma unroll
      for (int t = 0; t < 2; ++t) {
        int col = cbase + t * 16 + l15;
#pragma unroll
        for (int e = 0; e < 8; ++e) {
          int row = min(base + kb + e, kN - 1);   // clamp: Adh=0 past 100
          bF[t][e] = H[(size_t)row * W + col];
        }
      }
#pragma unroll
      for (int mt = 0; mt < 7; ++mt) {
        half8 aF = *(const half8*)&Adh[(mt * 16 + l15) * kAhS + kb];
        acc[mt][0] = __builtin_amdgcn_mfma_f32_16x16x32_f16(aF, bF[0], acc[mt][0], 0, 0, 0);
        acc[mt][1] = __builtin_amdgcn_mfma_f32_16x16x32_f16(aF, bF[1], acc[mt][1], 0, 0, 0);
      }
    }
    float bv0 = bias[cbase + l15];
    float bv1 = bias[cbase + 16 + l15];
#pragma unroll
    for (int mt = 0; mt < 7; ++mt)
#pragma unroll
      for (int q = 0; q < 4; ++q) {
        acc[mt][0][q] = fmaxf(acc[mt][0][q] + bv0, 0.f);   // relu
        acc[mt][1][q] = fmaxf(acc[mt][1][q] + bv1, 0.f);
      }
    // column sums (both STATS and SEGBN need them)
    float s0 = 0.f, s20 = 0.f, s1 = 0.f, s21 = 0.f;
#pragma unroll
    for (int mt = 0; mt < 7; ++mt)
#pragma unroll
      for (int q = 0; q < 4; ++q) {
        int row = mt * 16 + lg * 4 + q;
        if (row < 100) {
          float v0 = acc[mt][0][q], v1 = acc[mt][1][q];
          s0 += v0; s20 += v0 * v0; s1 += v1; s21 += v1 * v1;
        }
      }
    s0 += __shfl_xor(s0, 16, 64);  s0 += __shfl_xor(s0, 32, 64);
    s20 += __shfl_xor(s20, 16, 64); s20 += __shfl_xor(s20, 32, 64);
    s1 += __shfl_xor(s1, 16, 64);  s1 += __shfl_xor(s1, 32, 64);
    s21 += __shfl_xor(s21, 16, 64); s21 += __shfl_xor(s21, 32, 64);
    if (yb == 0) {
      if (lg == 0) {
        PST[(size_t)g * 512 + cbase + l15] = s0;
        PST[(size_t)g * 512 + 256 + cbase + l15] = s20;
        PST[(size_t)g * 512 + cbase + 16 + l15] = s1;
        PST[(size_t)g * 512 + 256 + cbase + 16 + l15] = s21;
      }
    } else {
      float m0 = s0 / 100.f, r0 = rsqrtf(s20 / 100.f - m0 * m0 + BN_EPS);
      float m1 = s1 / 100.f, r1 = rsqrtf(s21 / 100.f - m1 * m1 + BN_EPS);
#pragma unroll
      for (int mt = 0; mt < 7; ++mt)
#pragma unroll
        for (int q = 0; q < 4; ++q) {
          acc[mt][0][q] = (acc[mt][0][q] - m0) * r0;
          acc[mt][1][q] = (acc[mt][1][q] - m1) * r1;
        }
    }
#pragma unroll
    for (int mt = 0; mt < 7; ++mt)
#pragma unroll
      for (int q = 0; q < 4; ++q) {
        int row = mt * 16 + lg * 4 + q;
        if (row < 100) {
          OUT[(size_t)(base + row) * W + cbase + l15] = (_Float16)acc[mt][0][q];
          OUT[(size_t)(base + row) * W + cbase + 16 + l15] = (_Float16)acc[mt][1][q];
        }
      }
  } else {
    const int mt = wv;                 // waves 0..6 active
    f32x4 acc[8];
#pragma unroll
    for (int nt = 0; nt < 8; ++nt) acc[nt] = (f32x4){0.f, 0.f, 0.f, 0.f};
    if (mt < 7) {
#pragma unroll
      for (int k0 = 0; k0 < 128; k0 += 32) {
        const int kb = k0 + lg * 8;
        half8 aF = *(const half8*)&Adh[(mt * 16 + l15) * kAhS + kb];
#pragma unroll
        for (int nt = 0; nt < 8; ++nt) {
          half8 bF = *(const half8*)&Hst[(nt * 16 + l15) * kAhS + kb];
          acc[nt] = __builtin_amdgcn_mfma_f32_16x16x32_f16(aF, bF, acc[nt], 0, 0, 0);
        }
      }
#pragma unroll
      for (int nt = 0; nt < 8; ++nt) {
        float bvn = bias[nt * 16 + l15];
#pragma unroll
        for (int q = 0; q < 4; ++q) acc[nt][q] += bvn;
      }
      // row l2-normalize
#pragma unroll
      for (int q = 0; q < 4; ++q) {
        float ss = 0.f;
#pragma unroll
        for (int nt = 0; nt < 8; ++nt) ss += acc[nt][q] * acc[nt][q];
        ss += __shfl_xor(ss, 1, 64); ss += __shfl_xor(ss, 2, 64);
        ss += __shfl_xor(ss, 4, 64); ss += __shfl_xor(ss, 8, 64);
        float inv = 1.f / fmaxf(sqrtf(ss), 1e-12f);
#pragma unroll
        for (int nt = 0; nt < 8; ++nt) acc[nt][q] *= inv;
      }
    }
    if (yb == 0) {
      // per-node z (f32) + z16 (fp16) stores
      float* OZ = (float*)OUT0;
      if (mt < 7) {
#pragma unroll
        for (int nt = 0; nt < 8; ++nt)
#pragma unroll
          for (int q = 0; q < 4; ++q) {
            int row = mt * 16 + lg * 4 + q;
            if (row < 100) {
              OZ[(size_t)(base + row) * 128 + nt * 16 + l15] = acc[nt][q];
              Z16[(size_t)(base + row) * 128 + nt * 16 + l15] = (_Float16)acc[nt][q];
            }
          }
      }
      // col-max of z and z+noise
      float m1[8], m2[8];
#pragma unroll
      for (int nt = 0; nt < 8; ++nt) { m1[nt] = -INFINITY; m2[nt] = -INFINITY; }
      if (mt < 7) {
#pragma unroll
        for (int nt = 0; nt < 8; ++nt)
#pragma unroll
          for (int q = 0; q < 4; ++q) {
            int row = mt * 16 + lg * 4 + q;
            if (row < 100) {
              float zv = acc[nt][q];
              float nv = NOI[(size_t)(base + row) * 128 + nt * 16 + l15];
              m1[nt] = fmaxf(m1[nt], zv);
              m2[nt] = fmaxf(m2[nt], zv + nv);
            }
          }
#pragma unroll
        for (int nt = 0; nt < 8; ++nt) {
          m1[nt] = fmaxf(m1[nt], __shfl_xor(m1[nt], 16, 64));
          m1[nt] = fmaxf(m1[nt], __shfl_xor(m1[nt], 32, 64));
          m2[nt] = fmaxf(m2[nt], __shfl_xor(m2[nt], 16, 64));
          m2[nt] = fmaxf(m2[nt], __shfl_xor(m2[nt], 32, 64));
        }
      }
      __syncthreads();                  // cnt32/Adh dead -> scratch
      if (mt < 7 && lg == 0)
#pragma unroll
        for (int nt = 0; nt < 8; ++nt) {
          scr[wv * 128 + nt * 16 + l15] = m1[nt];
          scr[1024 + wv * 128 + nt * 16 + l15] = m2[nt];
        }
      __syncthreads();
      if (tid < 128) {
        float a = -INFINITY, b = -INFINITY;
        for (int w2 = 0; w2 < 7; ++w2) {
          a = fmaxf(a, scr[w2 * 128 + tid]);
          b = fmaxf(b, scr[1024 + w2 * 128 + tid]);
        }
        ZG[(size_t)g * 128 + tid] = a;
        ZZ[(size_t)g * 128 + tid] = a;
        ZZ[(size_t)(500 + g) * 128 + tid] = b;
      }
    } else {
      // mean-pool -> OUT[g][128]
      float* OP = (yb == 1) ? (float*)OUT1 : (float*)OUT2;
      float ps[8];
#pragma unroll
      for (int nt = 0; nt < 8; ++nt) ps[nt] = 0.f;
      if (mt < 7) {
#pragma unroll
        for (int nt = 0; nt < 8; ++nt)
#pragma unroll
          for (int q = 0; q < 4; ++q) {
            int row = mt * 16 + lg * 4 + q;
            if (row < 100) ps[nt] += acc[nt][q];
          }
      }
#pragma unroll
      for (int nt = 0; nt < 8; ++nt) {
        ps[nt] += __shfl_xor(ps[nt], 16, 64);
        ps[nt] += __shfl_xor(ps[nt], 32, 64);
      }
      __syncthreads();
      if (mt < 7 && lg == 0)
#pragma unroll
        for (int nt = 0; nt < 8; ++nt) scr[wv * 128 + nt * 16 + l15] = ps[nt];
      __syncthreads();
      if (tid < 128) {
        float s = 0.f;
        for (int w2 = 0; w2 < 7; ++w2) s += scr[w2 * 128 + tid];
        OP[(size_t)g * 128 + tid] = s / 100.f;
      }
    }
  }
}

// ============ BN finalize: sum 500 per-graph partials (fixed order) ============
__global__ __launch_bounds__(256)
void bn_red_k(const float* __restrict__ P, float* __restrict__ stats)
{
  const int c = threadIdx.x;
  float s = 0.f, s2 = 0.f;
  for (int b = 0; b < 500; ++b) {
    s  += P[(size_t)b * 512 + c];
    s2 += P[(size_t)b * 512 + 256 + c];
  }
  float m = s / (float)kN;
  float v = s2 / (float)kN - m * m;
  stats[512 + c] = m;
  stats[768 + c] = rsqrtf(v + BN_EPS);
}

// column-parallel BN, in place (target path)
__global__ __launch_bounds__(64)
void bn_cols_k(float* __restrict__ X, int rows, int cols)
{
  const int c = blockIdx.x, t = threadIdx.x;
  float s = 0.f, s2 = 0.f;
  for (int r = t; r < rows; r += 64) {
    float v = X[(size_t)r * cols + c];
    s += v; s2 += v * v;
  }
#pragma unroll
  for (int o = 32; o; o >>= 1) { s += __shfl_xor(s, o, 64); s2 += __shfl_xor(s2, o, 64); }
  float m = s / (float)rows;
  float var = s2 / (float)rows - m * m;
  float rinv = rsqrtf(var + BN_EPS);
  for (int r = t; r < rows; r += 64)
    X[(size_t)r * cols + c] = (X[(size_t)r * cols + c] - m) * rinv;
}

// row-wise L2 normalize (128 cols) — target path
__global__ __launch_bounds__(256)
void l2n_k(const float* __restrict__ X, float* __restrict__ Y, int rows)
{
  const int w = threadIdx.x >> 6, lane = threadIdx.x & 63;
  const int row = blockIdx.x * 4 + w;
  if (row >= rows) return;
  float2 v = *(const float2*)&X[(size_t)row * kH2 + lane * 2];
  float ss = v.x * v.x + v.y * v.y;
#pragma unroll
  for (int o = 32; o; o >>= 1) ss += __shfl_xor(ss, o, 64);
  float inv = 1.f / fmaxf(sqrtf(ss), 1e-12f);
  *(float2*)&Y[(size_t)row * kH2 + lane * 2] = make_float2(v.x * inv, v.y * inv);
}

// =========================================================================
extern "C" void kernel_launch(void* const* d_in, const int* in_sizes, int n_in,
                              void* d_out, int out_size, void* d_ws, size_t ws_size,
                              hipStream_t stream)
{
  const float* x        = (const float*)d_in[0];
  const int*   srcI     = (const int*)d_in[1];
  const int*   dstI     = (const int*)d_in[2];
  const float* pos_x    = (const float*)d_in[4];
  const int*   psrc     = (const int*)d_in[5];
  const int*   pdst     = (const int*)d_in[6];
  const float* neg_x    = (const float*)d_in[8];
  const int*   nsrc     = (const int*)d_in[9];
  const int*   ndst     = (const int*)d_in[10];
  const float* target_x = (const float*)d_in[12];
  const float* noise    = (const float*)d_in[13];
  const float* W_enc1   = (const float*)d_in[14];
  const float* b_enc1   = (const float*)d_in[15];
  const float* W_enc2   = (const float*)d_in[16];
  const float* b_enc2   = (const float*)d_in[17];
  const float* W_dec1   = (const float*)d_in[18];
  const float* W_dec2   = (const float*)d_in[19];
  const float* Wn1      = (const float*)d_in[20];
  const float* bn1      = (const float*)d_in[21];
  const float* Wn2      = (const float*)d_in[22];
  const float* bn2      = (const float*)d_in[23];
  const float* Ws1      = (const float*)d_in[24];
  const float* bs1      = (const float*)d_in[25];
  const float* Wp1      = (const float*)d_in[26];
  const float* bp1      = (const float*)d_in[27];
  const float* Wp2      = (const float*)d_in[28];
  const float* bp2      = (const float*)d_in[29];

  float* out  = (float*)d_out;
  float* o_z   = out;                 // N x 128
  float* o_zg  = out + 6400000;       // 500 x 128
  float* o_xr  = out + 6464000;       // N x 128
  float* o_pos = out + 12864000;      // 500 x 128
  float* o_neg = out + 12928000;
  float* o_zgm = out + 12992000;      // o_zgm||o_zpm contiguous 1000 x 128
  float* o_tz  = out + 13120000;

  // WORKSPACE MAP (float offsets), 3-wide schedule. Quarters Q0..Q3 plus
  // d_out's o_z / o_xr regions used as PRE-WRITE scratch (each consumed
  // before its real producer writes it; all stream-ordered; r2-r4 audit):
  //  step2 L1x3:  x/pos/neg -> Q0,Q1,Q2 (fp16 Nx256)
  //  step3 agg256x3: Q0..Q2 -> Q3, oZ-region, oXr-region (fp16 Nx256);
  //                  pstat -> out+12864000 (o_pos.. region, written later)
  //  step5 L2x3:  Q3/oZ/oXr -> Q0,Q1,Q2 (fp16 Nx128)
  //  step6 agg128x3: Q0..Q2 -> o_z(+z16=Q3), o_pos, o_neg; zz -> ws+22.4M
  //  step7/8 decode: z16(Q3) -> hDec(Q0) -> o_xr
  //  target path last: t1=ws+6.4M, t2=ws+6.7M (Q1 dead)
  float* ws = (float*)d_ws;
  _Float16* q0 = (_Float16*)ws;
  _Float16* q1 = (_Float16*)(ws + 6400000);
  _Float16* q2 = (_Float16*)(ws + 12800000);
  _Float16* q3 = (_Float16*)(ws + 19200000);
  _Float16* oZq = (_Float16*)o_z;      // scratch until step5
  _Float16* oXq = (_Float16*)o_xr;     // scratch until step5
  float* pstat = out + 12864000;       // 256000 f32, consumed by bn_red (step4)
  _Float16* hWt = (_Float16*)(ws + 25600000);
  float* stats = ws + 25700000;        // 1024
  float* zz    = ws + 22400000;        // 1000 x 128 (Q3 tail, after z16's 3.2M)
  float* t1000 = ws + 22600000;
  float* t1    = ws + 6400000;         // target-time (Q1 dead)
  float* t2    = ws + 6700000;
  _Float16* z16 = q3;                  // N x 128 fp16 (3.2M floats)
  if (ws_size < (size_t)(25921024) * sizeof(float)) return;

  _Float16* WtEnc1 = hWt;
  _Float16* WtEnc2 = hWt + 32768;
  _Float16* WtDec1 = hWt + 65536;
  _Float16* WtDec2 = hWt + 98304;
  _Float16* WtS1   = hWt + 131072;

  (void)hipFuncSetAttribute((const void*)gcn_agg3_k<128>,
      hipFuncAttributeMaxDynamicSharedMemorySize, kAggLds128);

  const dim3 gB3(782, 2, 3);
  const dim3 gC3(782, 1, 3);
  const dim3 gB1(782, 2, 1);
  const dim3 gC1(782, 1, 1);
  auto gg = [](int M, int Nc) {
    return dim3((unsigned)((M + 127) / 128), (unsigned)(Nc / 64), 1);
  };

  // 1. weight prep
  wprep_k<<<640, 256, 0, stream>>>(W_enc1, W_enc2, W_dec1, W_dec2, Ws1, hWt);

  // 2. layer-1 GEMMs, 3-wide: {x,pos,neg} @ {Enc1,S1,S1} -> Q0,Q1,Q2
  gemm_direct_k<0, 0, 128, 256, float, _Float16><<<gB3, 256, 0, stream>>>(
      x, pos_x, neg_x, WtEnc1, WtS1, WtS1, nullptr, q0, q1, q2, kN);

  // 3. agg256 x3: Q0..Q2 -> Q3, oZq, oXq (+pstat for main)
  gcn_agg3_k<256><<<dim3(kB, 3), 512, kAggLds256, stream>>>(
      q0, q1, q2, srcI, psrc, nsrc, dstI, pdst, ndst, b_enc1, bs1,
      q3, oZq, oXq, nullptr, pstat, nullptr, nullptr, nullptr);

  // 4. BN finalize
  bn_red_k<<<1, 256, 0, stream>>>(pstat, stats);

  // 5. layer-2 GEMMs, 3-wide (BN transform only z==0): -> Q0,Q1,Q2 (Nx128)
  gemm_direct_k<0, 2, 256, 128, _Float16, _Float16><<<gC3, 256, 0, stream>>>(
      q3, oZq, oXq, WtEnc2, WtEnc2, WtEnc2, stats + 512, q0, q1, q2, kN);

  // 6. agg128 x3: Q0..Q2 -> o_z(+z16), o_pos, o_neg; ZG/ZZ for main
  gcn_agg3_k<128><<<dim3(kB, 3), 512, kAggLds128, stream>>>(
      q0, q1, q2, srcI, psrc, nsrc, dstI, pdst, ndst, b_enc2, b_enc2,
      o_z, o_pos, o_neg, noise, nullptr, o_zg, zz, z16);

  // 7-8. decode: z16(Q3) -> hDec(Q0) -> o_xr
  gemm_direct_k<1, 0, 128, 256, _Float16, _Float16><<<gB1, 256, 0, stream>>>(
      z16, z16, z16, WtDec1, WtDec1, WtDec1, nullptr, q0, q0, q0, kN);
  gemm_direct_k<2, 0, 256, 128, _Float16, float><<<gC1, 256, 0, stream>>>(
      q0, q0, q0, WtDec2, WtDec2, WtDec2, nullptr, o_xr, o_xr, o_xr, kN);

  // 9-10. merged projection heads: zz -> t1000 -> o_zgm||o_zpm
  gemm_k<1><<<gg(1000, kH2), 256, 0, stream>>>(zz, Wp1, bp1, t1000, 1000, kH2, kH2);
  gemm_k<0><<<gg(1000, kH2), 256, 0, stream>>>(t1000, Wp2, bp2, o_zgm, 1000, kH2, kH2);

  // 11-14. target node encoder
  gemm_k<1><<<gg(kB, kH1), 256, 0, stream>>>(target_x, Wn1, bn1, t1, kB, kF0, kH1);
  bn_cols_k<<<256, 64, 0, stream>>>(t1, kB, kH1);
  gemm_k<0><<<gg(kB, kH2), 256, 0, stream>>>(t1, Wn2, bn2, t2, kB, kH1, kH2);
  l2n_k<<<125, 256, 0, stream>>>(t2, o_tz, kB);

  (void)in_sizes; (void)n_in; (void)out_size;
}

// Round 16
// 366.602 us; speedup vs baseline: 1.0299x; 1.0299x over previous
//
#include <hip/hip_runtime.h>
#include <math.h>

static constexpr int kN   = 50000;
static constexpr int kB   = 500;
static constexpr int kNPG = 100;
static constexpr int kEPG = 1600;
static constexpr int kESG = 800;
static constexpr int kF0  = 128;
static constexpr int kH1  = 256;
static constexpr int kH2  = 128;
#define BN_EPS 1e-5f

typedef _Float16 half8 __attribute__((ext_vector_type(8)));
typedef __attribute__((ext_vector_type(4))) float f32x4;

static constexpr int kCntW = 33;
static constexpr int kAhS  = 136;
// LDS (bytes): cnt32 u32[112][33] @0 (14784) | Adh fp16[112][136] @14784
// (30464) | Hst fp16[128][136] @45248 (34816). Total 80064 -> 2 blocks/CU.
static constexpr unsigned kAggLds = 80064;

// ============ weight prep: W[K][Nc] f32 -> Wt[(kg*Nc + c)*8 + e] fp16 ============
__global__ __launch_bounds__(256)
void wprep_k(const float* __restrict__ s0, const float* __restrict__ s1,
             const float* __restrict__ s2, const float* __restrict__ s3,
             const float* __restrict__ s4, _Float16* __restrict__ d)
{
  int seg = blockIdx.x >> 7;
  int idx = (blockIdx.x & 127) * 256 + threadIdx.x;
  const float* S; int Nc;
  switch (seg) {
    case 0: S = s0; Nc = 256; break;
    case 1: S = s1; Nc = 128; break;
    case 2: S = s2; Nc = 256; break;
    case 3: S = s3; Nc = 128; break;
    default: S = s4; Nc = 256; break;
  }
  int e = idx & 7, t = idx >> 3;
  int c = t % Nc, kg = t / Nc;
  d[seg * 32768 + idx] = (_Float16)S[(size_t)(kg * 8 + e) * Nc + c];
}

// ================= direct-global fp16 MFMA GEMM, 3-wide batched =================
// blockIdx.z selects (A,Wt,C). TRANSM: 0=none, 1=always, 2=only z==0.
// Wave tile 32x64, double-buffered k-steps, A-rows clamped, stores guarded.
// NOTE: A and C must NOT alias (cross-block race — r2..r4 lesson).
template<int ACT, int TRANSM, int K, int NC, typename AT, typename OT>
__global__ __launch_bounds__(256)
void gemm_direct_k(const AT* __restrict__ A0, const AT* __restrict__ A1, const AT* __restrict__ A2,
                   const _Float16* __restrict__ Wt0, const _Float16* __restrict__ Wt1,
                   const _Float16* __restrict__ Wt2, const float* __restrict__ tr,
                   OT* __restrict__ C0, OT* __restrict__ C1, OT* __restrict__ C2, int M)
{
  constexpr int NK = K / 32;
  const int zb = blockIdx.z;
  const AT* A = (zb == 0) ? A0 : (zb == 1) ? A1 : A2;
  const _Float16* Wt = (zb == 0) ? Wt0 : (zb == 1) ? Wt1 : Wt2;
  OT* C = (zb == 0) ? C0 : (zb == 1) ? C1 : C2;
  const bool doTr = (TRANSM == 1) || (TRANSM == 2 && zb == 0);
  const int tid = threadIdx.x;
  const int lane = tid & 63;
  const int l15 = lane & 15, lg = lane >> 4;
  const int wave = tid >> 6;
  const int wm = wave >> 1, wn = wave & 1;
  const int bm = blockIdx.x * 64;
  const int bn = blockIdx.y * 128;
  f32x4 acc[2][4];
#pragma unroll
  for (int m = 0; m < 2; ++m)
#pragma unroll
    for (int n = 0; n < 4; ++n) acc[m][n] = (f32x4){0.f, 0.f, 0.f, 0.f};

  int arow[2];
#pragma unroll
  for (int m = 0; m < 2; ++m)
    arow[m] = min(bm + wm * 32 + m * 16 + l15, M - 1);
  const int bcol = bn + wn * 64 + l15;

  half8  bBuf[2][4];
  float4 aRF[2][2][2];
  half8  aRH[2][2];

  {
#pragma unroll
    for (int n = 0; n < 4; ++n)
      bBuf[0][n] = *(const half8*)&Wt[((size_t)lg * NC + bcol + n * 16) * 8];
    const int kb = lg * 8;
#pragma unroll
    for (int m = 0; m < 2; ++m) {
      if constexpr (sizeof(AT) == 4) {
        const float* ap = (const float*)A + (size_t)arow[m] * K + kb;
        aRF[0][m][0] = *(const float4*)ap;
        aRF[0][m][1] = *(const float4*)(ap + 4);
      } else {
        aRH[0][m] = *(const half8*)((const _Float16*)A + (size_t)arow[m] * K + kb);
      }
    }
  }

#pragma unroll
  for (int ks = 0; ks < NK; ++ks) {
    const int cur = ks & 1, nxt = cur ^ 1;
    if (ks + 1 < NK) {
      const int kbn = (ks + 1) * 32 + lg * 8;
#pragma unroll
      for (int n = 0; n < 4; ++n)
        bBuf[nxt][n] = *(const half8*)&Wt[((size_t)((ks + 1) * 4 + lg) * NC + bcol + n * 16) * 8];
#pragma unroll
      for (int m = 0; m < 2; ++m) {
        if constexpr (sizeof(AT) == 4) {
          const float* ap = (const float*)A + (size_t)arow[m] * K + kbn;
          aRF[nxt][m][0] = *(const float4*)ap;
          aRF[nxt][m][1] = *(const float4*)(ap + 4);
        } else {
          aRH[nxt][m] = *(const half8*)((const _Float16*)A + (size_t)arow[m] * K + kbn);
        }
      }
    }
    const int kb0 = ks * 32 + lg * 8;
    half8 aF[2];
#pragma unroll
    for (int m = 0; m < 2; ++m) {
      half8 sa;
      if constexpr (sizeof(AT) == 4) {
        float va[8] = {aRF[cur][m][0].x, aRF[cur][m][0].y, aRF[cur][m][0].z, aRF[cur][m][0].w,
                       aRF[cur][m][1].x, aRF[cur][m][1].y, aRF[cur][m][1].z, aRF[cur][m][1].w};
        if (doTr) {
#pragma unroll
          for (int j = 0; j < 8; ++j) va[j] = (va[j] - tr[kb0 + j]) * tr[256 + kb0 + j];
        }
#pragma unroll
        for (int j = 0; j < 8; ++j) sa[j] = (_Float16)va[j];
      } else {
        if (doTr) {
#pragma unroll
          for (int j = 0; j < 8; ++j)
            sa[j] = (_Float16)(((float)aRH[cur][m][j] - tr[kb0 + j]) * tr[256 + kb0 + j]);
        } else {
          sa = aRH[cur][m];
        }
      }
      aF[m] = sa;
    }
#pragma unroll
    for (int m = 0; m < 2; ++m)
#pragma unroll
      for (int n = 0; n < 4; ++n)
        acc[m][n] = __builtin_amdgcn_mfma_f32_16x16x32_f16(aF[m], bBuf[cur][n], acc[m][n], 0, 0, 0);
  }
#pragma unroll
  for (int m = 0; m < 2; ++m) {
    int row_b = bm + wm * 32 + m * 16 + lg * 4;
#pragma unroll
    for (int q = 0; q < 4; ++q) {
      int row = row_b + q;
      if (row >= M) continue;
#pragma unroll
      for (int n = 0; n < 4; ++n) {
        float v = acc[m][n][q];
        if (ACT == 1) v = fmaxf(v, 0.f);
        else if (ACT == 2) v = 1.f / (1.f + expf(-v));
        C[(size_t)row * NC + bn + wn * 64 + n * 16 + l15] = (OT)v;
      }
    }
  }
}

// ======================= small-M tiled f32 GEMM (M<=1000 paths) =======================
template<int ACT>
__global__ __launch_bounds__(256)
void gemm_k(const float* __restrict__ A, const float* __restrict__ W,
            const float* __restrict__ bias, float* __restrict__ C,
            int M, int K, int Nc)
{
  __shared__ float As[32][136];
  __shared__ float Ws[32][68];
  const int tid = threadIdx.x;
  const int bm = blockIdx.x * 128;
  const int bn = blockIdx.y * 64;
  const int tm = (tid & 15) * 8;
  const int tn = (tid >> 4) * 4;
  float acc[8][4];
#pragma unroll
  for (int i = 0; i < 8; ++i)
#pragma unroll
    for (int j = 0; j < 4; ++j) acc[i][j] = 0.f;

  for (int k0 = 0; k0 < K; k0 += 32) {
#pragma unroll
    for (int l = 0; l < 4; ++l) {
      int idx = tid + l * 256;
      int r = idx >> 3;
      int kq = (idx & 7) << 2;
      int gr = bm + r;
      float4 v = make_float4(0.f, 0.f, 0.f, 0.f);
      if (gr < M) v = *(const float4*)&A[(size_t)gr * K + k0 + kq];
      As[kq + 0][r] = v.x; As[kq + 1][r] = v.y;
      As[kq + 2][r] = v.z; As[kq + 3][r] = v.w;
    }
#pragma unroll
    for (int l = 0; l < 2; ++l) {
      int idx = tid + l * 256;
      int r = idx >> 4;
      int nq = (idx & 15) << 2;
      *(float4*)&Ws[r][nq] = *(const float4*)&W[(size_t)(k0 + r) * Nc + bn + nq];
    }
    __syncthreads();
#pragma unroll
    for (int kk = 0; kk < 32; ++kk) {
      float4 a0 = *(float4*)&As[kk][tm];
      float4 a1 = *(float4*)&As[kk][tm + 4];
      float4 w4 = *(float4*)&Ws[kk][tn];
      float am[8] = {a0.x, a0.y, a0.z, a0.w, a1.x, a1.y, a1.z, a1.w};
      float wn4[4] = {w4.x, w4.y, w4.z, w4.w};
#pragma unroll
      for (int i = 0; i < 8; ++i)
#pragma unroll
        for (int j = 0; j < 4; ++j) acc[i][j] += am[i] * wn4[j];
    }
    __syncthreads();
  }
  float4 bv = make_float4(0.f, 0.f, 0.f, 0.f);
  if (bias) bv = *(const float4*)&bias[bn + tn];
#pragma unroll
  for (int i = 0; i < 8; ++i) {
    int row = bm + tm + i;
    if (row >= M) break;
    float o0 = acc[i][0] + bv.x, o1 = acc[i][1] + bv.y;
    float o2 = acc[i][2] + bv.z, o3 = acc[i][3] + bv.w;
    if (ACT == 1) {
      o0 = fmaxf(o0, 0.f); o1 = fmaxf(o1, 0.f);
      o2 = fmaxf(o2, 0.f); o3 = fmaxf(o3, 0.f);
    } else if (ACT == 2) {
      o0 = 1.f / (1.f + expf(-o0)); o1 = 1.f / (1.f + expf(-o1));
      o2 = 1.f / (1.f + expf(-o2)); o3 = 1.f / (1.f + expf(-o3));
    }
    *(float4*)&C[(size_t)row * Nc + bn + tn] = make_float4(o0, o1, o2, o3);
  }
}

// ================= 3-wide per-graph GCN aggregation, MFMA =================
// blockIdx.y: 0=main (epg=1600), 1=pos, 2=neg (epg=800).
// W=256: H staged TRANSPOSED in LDS in 2 column-halves (r15 fix: the 64
// uncoalesced scalar B-loads/lane were the 79us bottleneck). Per half:
// coalesced stage -> barrier -> MFMA with B-frag = 1x ds_read_b128 ->
// bias/relu -> column sums (STATS y==0 / SEGBN y>0, column-local) -> store.
// W=128: unchanged (already staged).
template<int W>
__global__ __launch_bounds__(512)
void gcn_agg3_k(const _Float16* __restrict__ H0, const _Float16* __restrict__ H1,
                const _Float16* __restrict__ H2,
                const int* __restrict__ src0, const int* __restrict__ src1,
                const int* __restrict__ src2,
                const int* __restrict__ dst0, const int* __restrict__ dst1,
                const int* __restrict__ dst2,
                const float* __restrict__ bias0, const float* __restrict__ bias12,
                void* __restrict__ OUT0, void* __restrict__ OUT1, void* __restrict__ OUT2,
                const float* __restrict__ NOI, float* __restrict__ PST,
                float* __restrict__ ZG, float* __restrict__ ZZ,
                _Float16* __restrict__ Z16)
{
  extern __shared__ __align__(16) unsigned lds_u[];
  unsigned* cnt32 = lds_u;                                   // [112][33] u32
  _Float16* Adh = (_Float16*)(lds_u + 112 * kCntW);          // [112][136]
  _Float16* Hst = (_Float16*)((char*)lds_u + 45248);         // [128][136]
  float* scr = (float*)lds_u;
  __shared__ int scnt[kNPG];
  __shared__ float sdinv[kNPG];
  const int yb = blockIdx.y;
  const _Float16* H = (yb == 0) ? H0 : (yb == 1) ? H1 : H2;
  const int* srcI = (yb == 0) ? src0 : (yb == 1) ? src1 : src2;
  const int* dstI = (yb == 0) ? dst0 : (yb == 1) ? dst1 : dst2;
  const float* bias = (yb == 0) ? bias0 : bias12;
  const int epg = (yb == 0) ? kEPG : kESG;
  const int g = blockIdx.x, tid = threadIdx.x;
  const int base = g * kNPG;
  const size_t ebase = (size_t)g * epg;
  const int lane = tid & 63, wv = tid >> 6;
  const int l15 = lane & 15, lg = lane >> 4;

  for (int i = tid; i < 112 * kCntW; i += 512) cnt32[i] = 0u;
  // zero Hst pad rows j 100..135 (never overwritten by staging)
  for (int i = tid; i < 128 * 18; i += 512) {
    int c = i / 18, w = i - c * 18;
    ((unsigned*)&Hst[c * kAhS + 100])[w] = 0u;
  }
  if (tid < kNPG) scnt[tid] = 0;
  __syncthreads();
  for (int e = tid; e < epg; e += 512) {
    int s = srcI[ebase + e] - base;
    int d = dstI[ebase + e] - base;
    atomicAdd(&scnt[d], 1);
    atomicAdd(&cnt32[d * kCntW + (s >> 2)], 1u << (8 * (s & 3)));
  }
  __syncthreads();
  if (tid < kNPG) sdinv[tid] = rsqrtf((float)scnt[tid] + 1.f);
  __syncthreads();
  for (int i = tid; i < 112 * kAhS; i += 512) {
    int d = i / kAhS, s = i - d * kAhS;
    float v = 0.f;
    if (d < 100 && s < 100) {
      unsigned w = cnt32[d * kCntW + (s >> 2)];
      unsigned c = (w >> (8 * (s & 3))) & 0xFFu;
      c += (s == d) ? 1u : 0u;
      v = (float)c * sdinv[s] * sdinv[d];
    }
    Adh[i] = (_Float16)v;
  }
  if constexpr (W == 128) {
    const int c = tid & 127;
    for (int j = tid >> 7; j < 100; j += 4)
      Hst[c * kAhS + j] = H[(size_t)(base + j) * 128 + c];
  }
  __syncthreads();

  if constexpr (W == 256) {
    _Float16* OUT = (yb == 0) ? (_Float16*)OUT0 : (yb == 1) ? (_Float16*)OUT1 : (_Float16*)OUT2;
#pragma unroll
    for (int half = 0; half < 2; ++half) {
      if (half) __syncthreads();          // protect Hst reuse from prior reads
      {
        const int c = tid & 127;
        for (int j = tid >> 7; j < 100; j += 4)
          Hst[c * kAhS + j] = H[(size_t)(base + j) * 256 + half * 128 + c];
      }
      __syncthreads();
      const int cb = wv * 16;             // this wave's 16-col group in half
      const int col = half * 128 + cb + l15;
      f32x4 acc[7];
#pragma unroll
      for (int mt = 0; mt < 7; ++mt) acc[mt] = (f32x4){0.f, 0.f, 0.f, 0.f};
#pragma unroll
      for (int k0 = 0; k0 < 128; k0 += 32) {
        const int kb = k0 + lg * 8;
        half8 bF = *(const half8*)&Hst[(cb + l15) * kAhS + kb];
#pragma unroll
        for (int mt = 0; mt < 7; ++mt) {
          half8 aF = *(const half8*)&Adh[(mt * 16 + l15) * kAhS + kb];
          acc[mt] = __builtin_amdgcn_mfma_f32_16x16x32_f16(aF, bF, acc[mt], 0, 0, 0);
        }
      }
      float bv = bias[col];
#pragma unroll
      for (int mt = 0; mt < 7; ++mt)
#pragma unroll
        for (int q = 0; q < 4; ++q)
          acc[mt][q] = fmaxf(acc[mt][q] + bv, 0.f);        // relu
      // column sums over rows (fixed order)
      float s0 = 0.f, s20 = 0.f;
#pragma unroll
      for (int mt = 0; mt < 7; ++mt)
#pragma unroll
        for (int q = 0; q < 4; ++q) {
          int row = mt * 16 + lg * 4 + q;
          if (row < 100) { float v = acc[mt][q]; s0 += v; s20 += v * v; }
        }
      s0 += __shfl_xor(s0, 16, 64);  s0 += __shfl_xor(s0, 32, 64);
      s20 += __shfl_xor(s20, 16, 64); s20 += __shfl_xor(s20, 32, 64);
      if (yb == 0) {
        if (lg == 0) {
          PST[(size_t)g * 512 + col] = s0;
          PST[(size_t)g * 512 + 256 + col] = s20;
        }
      } else {
        float m0 = s0 / 100.f, r0 = rsqrtf(s20 / 100.f - m0 * m0 + BN_EPS);
#pragma unroll
        for (int mt = 0; mt < 7; ++mt)
#pragma unroll
          for (int q = 0; q < 4; ++q)
            acc[mt][q] = (acc[mt][q] - m0) * r0;
      }
#pragma unroll
      for (int mt = 0; mt < 7; ++mt)
#pragma unroll
        for (int q = 0; q < 4; ++q) {
          int row = mt * 16 + lg * 4 + q;
          if (row < 100)
            OUT[(size_t)(base + row) * 256 + col] = (_Float16)acc[mt][q];
        }
    }
  } else {
    const int mt = wv;                 // waves 0..6 active
    f32x4 acc[8];
#pragma unroll
    for (int nt = 0; nt < 8; ++nt) acc[nt] = (f32x4){0.f, 0.f, 0.f, 0.f};
    if (mt < 7) {
#pragma unroll
      for (int k0 = 0; k0 < 128; k0 += 32) {
        const int kb = k0 + lg * 8;
        half8 aF = *(const half8*)&Adh[(mt * 16 + l15) * kAhS + kb];
#pragma unroll
        for (int nt = 0; nt < 8; ++nt) {
          half8 bF = *(const half8*)&Hst[(nt * 16 + l15) * kAhS + kb];
          acc[nt] = __builtin_amdgcn_mfma_f32_16x16x32_f16(aF, bF, acc[nt], 0, 0, 0);
        }
      }
#pragma unroll
      for (int nt = 0; nt < 8; ++nt) {
        float bvn = bias[nt * 16 + l15];
#pragma unroll
        for (int q = 0; q < 4; ++q) acc[nt][q] += bvn;
      }
#pragma unroll
      for (int q = 0; q < 4; ++q) {
        float ss = 0.f;
#pragma unroll
        for (int nt = 0; nt < 8; ++nt) ss += acc[nt][q] * acc[nt][q];
        ss += __shfl_xor(ss, 1, 64); ss += __shfl_xor(ss, 2, 64);
        ss += __shfl_xor(ss, 4, 64); ss += __shfl_xor(ss, 8, 64);
        float inv = 1.f / fmaxf(sqrtf(ss), 1e-12f);
#pragma unroll
        for (int nt = 0; nt < 8; ++nt) acc[nt][q] *= inv;
      }
    }
    if (yb == 0) {
      float* OZ = (float*)OUT0;
      if (mt < 7) {
#pragma unroll
        for (int nt = 0; nt < 8; ++nt)
#pragma unroll
          for (int q = 0; q < 4; ++q) {
            int row = mt * 16 + lg * 4 + q;
            if (row < 100) {
              OZ[(size_t)(base + row) * 128 + nt * 16 + l15] = acc[nt][q];
              Z16[(size_t)(base + row) * 128 + nt * 16 + l15] = (_Float16)acc[nt][q];
            }
          }
      }
      float m1[8], m2[8];
#pragma unroll
      for (int nt = 0; nt < 8; ++nt) { m1[nt] = -INFINITY; m2[nt] = -INFINITY; }
      if (mt < 7) {
#pragma unroll
        for (int nt = 0; nt < 8; ++nt)
#pragma unroll
          for (int q = 0; q < 4; ++q) {
            int row = mt * 16 + lg * 4 + q;
            if (row < 100) {
              float zv = acc[nt][q];
              float nv = NOI[(size_t)(base + row) * 128 + nt * 16 + l15];
              m1[nt] = fmaxf(m1[nt], zv);
              m2[nt] = fmaxf(m2[nt], zv + nv);
            }
          }
#pragma unroll
        for (int nt = 0; nt < 8; ++nt) {
          m1[nt] = fmaxf(m1[nt], __shfl_xor(m1[nt], 16, 64));
          m1[nt] = fmaxf(m1[nt], __shfl_xor(m1[nt], 32, 64));
          m2[nt] = fmaxf(m2[nt], __shfl_xor(m2[nt], 16, 64));
          m2[nt] = fmaxf(m2[nt], __shfl_xor(m2[nt], 32, 64));
        }
      }
      __syncthreads();
      if (mt < 7 && lg == 0)
#pragma unroll
        for (int nt = 0; nt < 8; ++nt) {
          scr[wv * 128 + nt * 16 + l15] = m1[nt];
          scr[1024 + wv * 128 + nt * 16 + l15] = m2[nt];
        }
      __syncthreads();
      if (tid < 128) {
        float a = -INFINITY, b = -INFINITY;
        for (int w2 = 0; w2 < 7; ++w2) {
          a = fmaxf(a, scr[w2 * 128 + tid]);
          b = fmaxf(b, scr[1024 + w2 * 128 + tid]);
        }
        ZG[(size_t)g * 128 + tid] = a;
        ZZ[(size_t)g * 128 + tid] = a;
        ZZ[(size_t)(500 + g) * 128 + tid] = b;
      }
    } else {
      float* OP = (yb == 1) ? (float*)OUT1 : (float*)OUT2;
      float ps[8];
#pragma unroll
      for (int nt = 0; nt < 8; ++nt) ps[nt] = 0.f;
      if (mt < 7) {
#pragma unroll
        for (int nt = 0; nt < 8; ++nt)
#pragma unroll
          for (int q = 0; q < 4; ++q) {
            int row = mt * 16 + lg * 4 + q;
            if (row < 100) ps[nt] += acc[nt][q];
          }
      }
#pragma unroll
      for (int nt = 0; nt < 8; ++nt) {
        ps[nt] += __shfl_xor(ps[nt], 16, 64);
        ps[nt] += __shfl_xor(ps[nt], 32, 64);
      }
      __syncthreads();
      if (mt < 7 && lg == 0)
#pragma unroll
        for (int nt = 0; nt < 8; ++nt) scr[wv * 128 + nt * 16 + l15] = ps[nt];
      __syncthreads();
      if (tid < 128) {
        float s = 0.f;
        for (int w2 = 0; w2 < 7; ++w2) s += scr[w2 * 128 + tid];
        OP[(size_t)g * 128 + tid] = s / 100.f;
      }
    }
  }
}

// ============ BN finalize: sum 500 per-graph partials (fixed order) ============
__global__ __launch_bounds__(256)
void bn_red_k(const float* __restrict__ P, float* __restrict__ stats)
{
  const int c = threadIdx.x;
  float s = 0.f, s2 = 0.f;
  for (int b = 0; b < 500; ++b) {
    s  += P[(size_t)b * 512 + c];
    s2 += P[(size_t)b * 512 + 256 + c];
  }
  float m = s / (float)kN;
  float v = s2 / (float)kN - m * m;
  stats[512 + c] = m;
  stats[768 + c] = rsqrtf(v + BN_EPS);
}

// column-parallel BN, in place (target path)
__global__ __launch_bounds__(64)
void bn_cols_k(float* __restrict__ X, int rows, int cols)
{
  const int c = blockIdx.x, t = threadIdx.x;
  float s = 0.f, s2 = 0.f;
  for (int r = t; r < rows; r += 64) {
    float v = X[(size_t)r * cols + c];
    s += v; s2 += v * v;
  }
#pragma unroll
  for (int o = 32; o; o >>= 1) { s += __shfl_xor(s, o, 64); s2 += __shfl_xor(s2, o, 64); }
  float m = s / (float)rows;
  float var = s2 / (float)rows - m * m;
  float rinv = rsqrtf(var + BN_EPS);
  for (int r = t; r < rows; r += 64)
    X[(size_t)r * cols + c] = (X[(size_t)r * cols + c] - m) * rinv;
}

// row-wise L2 normalize (128 cols) — target path
__global__ __launch_bounds__(256)
void l2n_k(const float* __restrict__ X, float* __restrict__ Y, int rows)
{
  const int w = threadIdx.x >> 6, lane = threadIdx.x & 63;
  const int row = blockIdx.x * 4 + w;
  if (row >= rows) return;
  float2 v = *(const float2*)&X[(size_t)row * kH2 + lane * 2];
  float ss = v.x * v.x + v.y * v.y;
#pragma unroll
  for (int o = 32; o; o >>= 1) ss += __shfl_xor(ss, o, 64);
  float inv = 1.f / fmaxf(sqrtf(ss), 1e-12f);
  *(float2*)&Y[(size_t)row * kH2 + lane * 2] = make_float2(v.x * inv, v.y * inv);
}

// =========================================================================
extern "C" void kernel_launch(void* const* d_in, const int* in_sizes, int n_in,
                              void* d_out, int out_size, void* d_ws, size_t ws_size,
                              hipStream_t stream)
{
  const float* x        = (const float*)d_in[0];
  const int*   srcI     = (const int*)d_in[1];
  const int*   dstI     = (const int*)d_in[2];
  const float* pos_x    = (const float*)d_in[4];
  const int*   psrc     = (const int*)d_in[5];
  const int*   pdst     = (const int*)d_in[6];
  const float* neg_x    = (const float*)d_in[8];
  const int*   nsrc     = (const int*)d_in[9];
  const int*   ndst     = (const int*)d_in[10];
  const float* target_x = (const float*)d_in[12];
  const float* noise    = (const float*)d_in[13];
  const float* W_enc1   = (const float*)d_in[14];
  const float* b_enc1   = (const float*)d_in[15];
  const float* W_enc2   = (const float*)d_in[16];
  const float* b_enc2   = (const float*)d_in[17];
  const float* W_dec1   = (const float*)d_in[18];
  const float* W_dec2   = (const float*)d_in[19];
  const float* Wn1      = (const float*)d_in[20];
  const float* bn1      = (const float*)d_in[21];
  const float* Wn2      = (const float*)d_in[22];
  const float* bn2      = (const float*)d_in[23];
  const float* Ws1      = (const float*)d_in[24];
  const float* bs1      = (const float*)d_in[25];
  const float* Wp1      = (const float*)d_in[26];
  const float* bp1      = (const float*)d_in[27];
  const float* Wp2      = (const float*)d_in[28];
  const float* bp2      = (const float*)d_in[29];

  float* out  = (float*)d_out;
  float* o_z   = out;                 // N x 128
  float* o_zg  = out + 6400000;       // 500 x 128
  float* o_xr  = out + 6464000;       // N x 128
  float* o_pos = out + 12864000;      // 500 x 128
  float* o_neg = out + 12928000;
  float* o_zgm = out + 12992000;      // o_zgm||o_zpm contiguous 1000 x 128
  float* o_tz  = out + 13120000;

  // WORKSPACE MAP — identical plan to r15 (audited); only the agg kernel's
  // internals changed.
  float* ws = (float*)d_ws;
  _Float16* q0 = (_Float16*)ws;
  _Float16* q1 = (_Float16*)(ws + 6400000);
  _Float16* q2 = (_Float16*)(ws + 12800000);
  _Float16* q3 = (_Float16*)(ws + 19200000);
  _Float16* oZq = (_Float16*)o_z;      // scratch until step5
  _Float16* oXq = (_Float16*)o_xr;     // scratch until step5
  float* pstat = out + 12864000;       // consumed by bn_red before o_pos written
  _Float16* hWt = (_Float16*)(ws + 25600000);
  float* stats = ws + 25700000;
  float* zz    = ws + 22400000;
  float* t1000 = ws + 22600000;
  float* t1    = ws + 6400000;
  float* t2    = ws + 6700000;
  _Float16* z16 = q3;
  if (ws_size < (size_t)(25921024) * sizeof(float)) return;

  _Float16* WtEnc1 = hWt;
  _Float16* WtEnc2 = hWt + 32768;
  _Float16* WtDec1 = hWt + 65536;
  _Float16* WtDec2 = hWt + 98304;
  _Float16* WtS1   = hWt + 131072;

  (void)hipFuncSetAttribute((const void*)gcn_agg3_k<256>,
      hipFuncAttributeMaxDynamicSharedMemorySize, kAggLds);
  (void)hipFuncSetAttribute((const void*)gcn_agg3_k<128>,
      hipFuncAttributeMaxDynamicSharedMemorySize, kAggLds);

  const dim3 gB3(782, 2, 3);
  const dim3 gC3(782, 1, 3);
  const dim3 gB1(782, 2, 1);
  const dim3 gC1(782, 1, 1);
  auto gg = [](int M, int Nc) {
    return dim3((unsigned)((M + 127) / 128), (unsigned)(Nc / 64), 1);
  };

  // 1. weight prep
  wprep_k<<<640, 256, 0, stream>>>(W_enc1, W_enc2, W_dec1, W_dec2, Ws1, hWt);

  // 2. layer-1 GEMMs, 3-wide
  gemm_direct_k<0, 0, 128, 256, float, _Float16><<<gB3, 256, 0, stream>>>(
      x, pos_x, neg_x, WtEnc1, WtS1, WtS1, nullptr, q0, q1, q2, kN);

  // 3. agg256 x3 (staged B): Q0..Q2 -> Q3, oZq, oXq (+pstat for main)
  gcn_agg3_k<256><<<dim3(kB, 3), 512, kAggLds, stream>>>(
      q0, q1, q2, srcI, psrc, nsrc, dstI, pdst, ndst, b_enc1, bs1,
      q3, oZq, oXq, nullptr, pstat, nullptr, nullptr, nullptr);

  // 4. BN finalize
  bn_red_k<<<1, 256, 0, stream>>>(pstat, stats);

  // 5. layer-2 GEMMs, 3-wide (BN transform only z==0)
  gemm_direct_k<0, 2, 256, 128, _Float16, _Float16><<<gC3, 256, 0, stream>>>(
      q3, oZq, oXq, WtEnc2, WtEnc2, WtEnc2, stats + 512, q0, q1, q2, kN);

  // 6. agg128 x3: Q0..Q2 -> o_z(+z16), o_pos, o_neg; ZG/ZZ for main
  gcn_agg3_k<128><<<dim3(kB, 3), 512, kAggLds, stream>>>(
      q0, q1, q2, srcI, psrc, nsrc, dstI, pdst, ndst, b_enc2, b_enc2,
      o_z, o_pos, o_neg, noise, nullptr, o_zg, zz, z16);

  // 7-8. decode: z16(Q3) -> Q0 -> o_xr
  gemm_direct_k<1, 0, 128, 256, _Float16, _Float16><<<gB1, 256, 0, stream>>>(
      z16, z16, z16, WtDec1, WtDec1, WtDec1, nullptr, q0, q0, q0, kN);
  gemm_direct_k<2, 0, 256, 128, _Float16, float><<<gC1, 256, 0, stream>>>(
      q0, q0, q0, WtDec2, WtDec2, WtDec2, nullptr, o_xr, o_xr, o_xr, kN);

  // 9-10. merged projection heads
  gemm_k<1><<<gg(1000, kH2), 256, 0, stream>>>(zz, Wp1, bp1, t1000, 1000, kH2, kH2);
  gemm_k<0><<<gg(1000, kH2), 256, 0, stream>>>(t1000, Wp2, bp2, o_zgm, 1000, kH2, kH2);

  // 11-14. target node encoder
  gemm_k<1><<<gg(kB, kH1), 256, 0, stream>>>(target_x, Wn1, bn1, t1, kB, kF0, kH1);
  bn_cols_k<<<256, 64, 0, stream>>>(t1, kB, kH1);
  gemm_k<0><<<gg(kB, kH2), 256, 0, stream>>>(t1, Wn2, bn2, t2, kB, kH1, kH2);
  l2n_k<<<125, 256, 0, stream>>>(t2, o_tz, kB);

  (void)in_sizes; (void)n_in; (void)out_size;
}

// Round 17
// 353.188 us; speedup vs baseline: 1.0690x; 1.0380x over previous
//
#include <hip/hip_runtime.h>
#include <math.h>

static constexpr int kN   = 50000;
static constexpr int kB   = 500;
static constexpr int kNPG = 100;
static constexpr int kEPG = 1600;
static constexpr int kESG = 800;
static constexpr int kF0  = 128;
static constexpr int kH1  = 256;
static constexpr int kH2  = 128;
#define BN_EPS 1e-5f

typedef _Float16 half8 __attribute__((ext_vector_type(8)));
typedef __attribute__((ext_vector_type(4))) float f32x4;

static constexpr int kCntW = 33;
static constexpr int kAhS  = 136;
// LDS (bytes): cnt32 u32[112][33] @0 (14784) | Adh fp16[112][136] @14784
// (30464) | Hst fp16[128][136] @45248 (34816). Total 80064 -> 2 blocks/CU.
static constexpr unsigned kAggLds = 80064;

// ============ weight prep: W[K][Nc] f32 -> Wt[(kg*Nc + c)*8 + e] fp16 ============
__global__ __launch_bounds__(256)
void wprep_k(const float* __restrict__ s0, const float* __restrict__ s1,
             const float* __restrict__ s2, const float* __restrict__ s3,
             const float* __restrict__ s4, _Float16* __restrict__ d)
{
  int seg = blockIdx.x >> 7;
  int idx = (blockIdx.x & 127) * 256 + threadIdx.x;
  const float* S; int Nc;
  switch (seg) {
    case 0: S = s0; Nc = 256; break;
    case 1: S = s1; Nc = 128; break;
    case 2: S = s2; Nc = 256; break;
    case 3: S = s3; Nc = 128; break;
    default: S = s4; Nc = 256; break;
  }
  int e = idx & 7, t = idx >> 3;
  int c = t % Nc, kg = t / Nc;
  d[seg * 32768 + idx] = (_Float16)S[(size_t)(kg * 8 + e) * Nc + c];
}

// ================= direct-global fp16 MFMA GEMM, 3-wide batched =================
// blockIdx.z selects (A,Wt,C). TRANSM: 0=none, 1=always, 2=only z==0.
// Wave tile 32x64, double-buffered k-steps, A-rows clamped, stores guarded.
// NOTE: A and C must NOT alias (cross-block race — r2..r4 lesson).
template<int ACT, int TRANSM, int K, int NC, typename AT, typename OT>
__global__ __launch_bounds__(256)
void gemm_direct_k(const AT* __restrict__ A0, const AT* __restrict__ A1, const AT* __restrict__ A2,
                   const _Float16* __restrict__ Wt0, const _Float16* __restrict__ Wt1,
                   const _Float16* __restrict__ Wt2, const float* __restrict__ tr,
                   OT* __restrict__ C0, OT* __restrict__ C1, OT* __restrict__ C2, int M)
{
  constexpr int NK = K / 32;
  const int zb = blockIdx.z;
  const AT* A = (zb == 0) ? A0 : (zb == 1) ? A1 : A2;
  const _Float16* Wt = (zb == 0) ? Wt0 : (zb == 1) ? Wt1 : Wt2;
  OT* C = (zb == 0) ? C0 : (zb == 1) ? C1 : C2;
  const bool doTr = (TRANSM == 1) || (TRANSM == 2 && zb == 0);
  const int tid = threadIdx.x;
  const int lane = tid & 63;
  const int l15 = lane & 15, lg = lane >> 4;
  const int wave = tid >> 6;
  const int wm = wave >> 1, wn = wave & 1;
  const int bm = blockIdx.x * 64;
  const int bn = blockIdx.y * 128;
  f32x4 acc[2][4];
#pragma unroll
  for (int m = 0; m < 2; ++m)
#pragma unroll
    for (int n = 0; n < 4; ++n) acc[m][n] = (f32x4){0.f, 0.f, 0.f, 0.f};

  int arow[2];
#pragma unroll
  for (int m = 0; m < 2; ++m)
    arow[m] = min(bm + wm * 32 + m * 16 + l15, M - 1);
  const int bcol = bn + wn * 64 + l15;

  half8  bBuf[2][4];
  float4 aRF[2][2][2];
  half8  aRH[2][2];

  {
#pragma unroll
    for (int n = 0; n < 4; ++n)
      bBuf[0][n] = *(const half8*)&Wt[((size_t)lg * NC + bcol + n * 16) * 8];
    const int kb = lg * 8;
#pragma unroll
    for (int m = 0; m < 2; ++m) {
      if constexpr (sizeof(AT) == 4) {
        const float* ap = (const float*)A + (size_t)arow[m] * K + kb;
        aRF[0][m][0] = *(const float4*)ap;
        aRF[0][m][1] = *(const float4*)(ap + 4);
      } else {
        aRH[0][m] = *(const half8*)((const _Float16*)A + (size_t)arow[m] * K + kb);
      }
    }
  }

#pragma unroll
  for (int ks = 0; ks < NK; ++ks) {
    const int cur = ks & 1, nxt = cur ^ 1;
    if (ks + 1 < NK) {
      const int kbn = (ks + 1) * 32 + lg * 8;
#pragma unroll
      for (int n = 0; n < 4; ++n)
        bBuf[nxt][n] = *(const half8*)&Wt[((size_t)((ks + 1) * 4 + lg) * NC + bcol + n * 16) * 8];
#pragma unroll
      for (int m = 0; m < 2; ++m) {
        if constexpr (sizeof(AT) == 4) {
          const float* ap = (const float*)A + (size_t)arow[m] * K + kbn;
          aRF[nxt][m][0] = *(const float4*)ap;
          aRF[nxt][m][1] = *(const float4*)(ap + 4);
        } else {
          aRH[nxt][m] = *(const half8*)((const _Float16*)A + (size_t)arow[m] * K + kbn);
        }
      }
    }
    const int kb0 = ks * 32 + lg * 8;
    half8 aF[2];
#pragma unroll
    for (int m = 0; m < 2; ++m) {
      half8 sa;
      if constexpr (sizeof(AT) == 4) {
        float va[8] = {aRF[cur][m][0].x, aRF[cur][m][0].y, aRF[cur][m][0].z, aRF[cur][m][0].w,
                       aRF[cur][m][1].x, aRF[cur][m][1].y, aRF[cur][m][1].z, aRF[cur][m][1].w};
        if (doTr) {
#pragma unroll
          for (int j = 0; j < 8; ++j) va[j] = (va[j] - tr[kb0 + j]) * tr[256 + kb0 + j];
        }
#pragma unroll
        for (int j = 0; j < 8; ++j) sa[j] = (_Float16)va[j];
      } else {
        if (doTr) {
#pragma unroll
          for (int j = 0; j < 8; ++j)
            sa[j] = (_Float16)(((float)aRH[cur][m][j] - tr[kb0 + j]) * tr[256 + kb0 + j]);
        } else {
          sa = aRH[cur][m];
        }
      }
      aF[m] = sa;
    }
#pragma unroll
    for (int m = 0; m < 2; ++m)
#pragma unroll
      for (int n = 0; n < 4; ++n)
        acc[m][n] = __builtin_amdgcn_mfma_f32_16x16x32_f16(aF[m], bBuf[cur][n], acc[m][n], 0, 0, 0);
  }
#pragma unroll
  for (int m = 0; m < 2; ++m) {
    int row_b = bm + wm * 32 + m * 16 + lg * 4;
#pragma unroll
    for (int q = 0; q < 4; ++q) {
      int row = row_b + q;
      if (row >= M) continue;
#pragma unroll
      for (int n = 0; n < 4; ++n) {
        float v = acc[m][n][q];
        if (ACT == 1) v = fmaxf(v, 0.f);
        else if (ACT == 2) v = 1.f / (1.f + expf(-v));
        C[(size_t)row * NC + bn + wn * 64 + n * 16 + l15] = (OT)v;
      }
    }
  }
}

// ================= fused decoder: o_xr = sigmoid(relu(z16@W1)@W2) =================
// One 64-row block: layer-1 (K=128 -> 64x256) -> relu -> LDS [64][264] fp16
// (C-frag writes 32B-contiguous/16 lanes; layer-2 ds_read_b128 2-way alias =
// free) -> layer-2 (K=256 -> 64x128) -> sigmoid -> o_xr. Removes the 51 MB
// hDec HBM round trip + one launch. 512 thr (8 waves), 33.8 KB LDS.
__global__ __launch_bounds__(512)
void dec_fused_k(const _Float16* __restrict__ Z, const _Float16* __restrict__ Wt1,
                 const _Float16* __restrict__ Wt2, float* __restrict__ XR, int M)
{
  __shared__ alignas(16) _Float16 Hrm[64][264];
  const int tid = threadIdx.x;
  const int lane = tid & 63;
  const int l15 = lane & 15, lg = lane >> 4;
  const int wave = tid >> 6;           // 0..7
  const int wm = wave >> 2;            // 0..1 : 32-row group (layer 1)
  const int wn = wave & 3;             // 0..3 : 64-col group (layer 1)
  const int bm = blockIdx.x * 64;

  // ---- layer 1: 64x256 = z(64x128) @ W1, wave tile 32x64
  f32x4 acc[2][4];
#pragma unroll
  for (int m = 0; m < 2; ++m)
#pragma unroll
    for (int n = 0; n < 4; ++n) acc[m][n] = (f32x4){0.f, 0.f, 0.f, 0.f};
  int arow[2];
#pragma unroll
  for (int m = 0; m < 2; ++m)
    arow[m] = min(bm + wm * 32 + m * 16 + l15, M - 1);
  const int bcol = wn * 64 + l15;
#pragma unroll
  for (int ks = 0; ks < 4; ++ks) {
    const int kb = ks * 32 + lg * 8;
    half8 bF[4];
#pragma unroll
    for (int n = 0; n < 4; ++n)
      bF[n] = *(const half8*)&Wt1[((size_t)(ks * 4 + lg) * 256 + bcol + n * 16) * 8];
    half8 aF[2];
#pragma unroll
    for (int m = 0; m < 2; ++m)
      aF[m] = *(const half8*)&Z[(size_t)arow[m] * 128 + kb];
#pragma unroll
    for (int m = 0; m < 2; ++m)
#pragma unroll
      for (int n = 0; n < 4; ++n)
        acc[m][n] = __builtin_amdgcn_mfma_f32_16x16x32_f16(aF[m], bF[n], acc[m][n], 0, 0, 0);
  }
  // relu -> LDS (local rows 0..63)
#pragma unroll
  for (int m = 0; m < 2; ++m)
#pragma unroll
    for (int q = 0; q < 4; ++q) {
      int lrow = wm * 32 + m * 16 + lg * 4 + q;
#pragma unroll
      for (int n = 0; n < 4; ++n)
        Hrm[lrow][wn * 64 + n * 16 + l15] = (_Float16)fmaxf(acc[m][n][q], 0.f);
    }
  __syncthreads();

  // ---- layer 2: 64x128 = Hrm(64x256) @ W2, wave tile 32x32
  const int wm2 = wave & 1, wn2 = wave >> 1;   // 2 row-groups x 4 col-groups
  f32x4 acc2[2][2];
#pragma unroll
  for (int m = 0; m < 2; ++m)
#pragma unroll
    for (int n = 0; n < 2; ++n) acc2[m][n] = (f32x4){0.f, 0.f, 0.f, 0.f};
#pragma unroll
  for (int ks = 0; ks < 8; ++ks) {
    const int kb = ks * 32 + lg * 8;
    half8 aF[2];
#pragma unroll
    for (int m = 0; m < 2; ++m)
      aF[m] = *(const half8*)&Hrm[wm2 * 32 + m * 16 + l15][kb];
    half8 bF[2];
#pragma unroll
    for (int n = 0; n < 2; ++n)
      bF[n] = *(const half8*)&Wt2[((size_t)(ks * 4 + lg) * 128 + wn2 * 32 + n * 16 + l15) * 8];
#pragma unroll
    for (int m = 0; m < 2; ++m)
#pragma unroll
      for (int n = 0; n < 2; ++n)
        acc2[m][n] = __builtin_amdgcn_mfma_f32_16x16x32_f16(aF[m], bF[n], acc2[m][n], 0, 0, 0);
  }
#pragma unroll
  for (int m = 0; m < 2; ++m)
#pragma unroll
    for (int q = 0; q < 4; ++q) {
      int row = bm + wm2 * 32 + m * 16 + lg * 4 + q;
      if (row >= M) continue;
#pragma unroll
      for (int n = 0; n < 2; ++n) {
        float v = acc2[m][n][q];
        XR[(size_t)row * 128 + wn2 * 32 + n * 16 + l15] = 1.f / (1.f + expf(-v));
      }
    }
}

// ======================= small-M tiled f32 GEMM (M<=1000 paths) =======================
template<int ACT>
__global__ __launch_bounds__(256)
void gemm_k(const float* __restrict__ A, const float* __restrict__ W,
            const float* __restrict__ bias, float* __restrict__ C,
            int M, int K, int Nc)
{
  __shared__ float As[32][136];
  __shared__ float Ws[32][68];
  const int tid = threadIdx.x;
  const int bm = blockIdx.x * 128;
  const int bn = blockIdx.y * 64;
  const int tm = (tid & 15) * 8;
  const int tn = (tid >> 4) * 4;
  float acc[8][4];
#pragma unroll
  for (int i = 0; i < 8; ++i)
#pragma unroll
    for (int j = 0; j < 4; ++j) acc[i][j] = 0.f;

  for (int k0 = 0; k0 < K; k0 += 32) {
#pragma unroll
    for (int l = 0; l < 4; ++l) {
      int idx = tid + l * 256;
      int r = idx >> 3;
      int kq = (idx & 7) << 2;
      int gr = bm + r;
      float4 v = make_float4(0.f, 0.f, 0.f, 0.f);
      if (gr < M) v = *(const float4*)&A[(size_t)gr * K + k0 + kq];
      As[kq + 0][r] = v.x; As[kq + 1][r] = v.y;
      As[kq + 2][r] = v.z; As[kq + 3][r] = v.w;
    }
#pragma unroll
    for (int l = 0; l < 2; ++l) {
      int idx = tid + l * 256;
      int r = idx >> 4;
      int nq = (idx & 15) << 2;
      *(float4*)&Ws[r][nq] = *(const float4*)&W[(size_t)(k0 + r) * Nc + bn + nq];
    }
    __syncthreads();
#pragma unroll
    for (int kk = 0; kk < 32; ++kk) {
      float4 a0 = *(float4*)&As[kk][tm];
      float4 a1 = *(float4*)&As[kk][tm + 4];
      float4 w4 = *(float4*)&Ws[kk][tn];
      float am[8] = {a0.x, a0.y, a0.z, a0.w, a1.x, a1.y, a1.z, a1.w};
      float wn4[4] = {w4.x, w4.y, w4.z, w4.w};
#pragma unroll
      for (int i = 0; i < 8; ++i)
#pragma unroll
        for (int j = 0; j < 4; ++j) acc[i][j] += am[i] * wn4[j];
    }
    __syncthreads();
  }
  float4 bv = make_float4(0.f, 0.f, 0.f, 0.f);
  if (bias) bv = *(const float4*)&bias[bn + tn];
#pragma unroll
  for (int i = 0; i < 8; ++i) {
    int row = bm + tm + i;
    if (row >= M) break;
    float o0 = acc[i][0] + bv.x, o1 = acc[i][1] + bv.y;
    float o2 = acc[i][2] + bv.z, o3 = acc[i][3] + bv.w;
    if (ACT == 1) {
      o0 = fmaxf(o0, 0.f); o1 = fmaxf(o1, 0.f);
      o2 = fmaxf(o2, 0.f); o3 = fmaxf(o3, 0.f);
    } else if (ACT == 2) {
      o0 = 1.f / (1.f + expf(-o0)); o1 = 1.f / (1.f + expf(-o1));
      o2 = 1.f / (1.f + expf(-o2)); o3 = 1.f / (1.f + expf(-o3));
    }
    *(float4*)&C[(size_t)row * Nc + bn + tn] = make_float4(o0, o1, o2, o3);
  }
}

// ================= 3-wide per-graph GCN aggregation, MFMA =================
// blockIdx.y: 0=main (epg=1600), 1=pos, 2=neg (epg=800). See r15/r16 notes.
template<int W>
__global__ __launch_bounds__(512)
void gcn_agg3_k(const _Float16* __restrict__ H0, const _Float16* __restrict__ H1,
                const _Float16* __restrict__ H2,
                const int* __restrict__ src0, const int* __restrict__ src1,
                const int* __restrict__ src2,
                const int* __restrict__ dst0, const int* __restrict__ dst1,
                const int* __restrict__ dst2,
                const float* __restrict__ bias0, const float* __restrict__ bias12,
                void* __restrict__ OUT0, void* __restrict__ OUT1, void* __restrict__ OUT2,
                const float* __restrict__ NOI, float* __restrict__ PST,
                float* __restrict__ ZG, float* __restrict__ ZZ,
                _Float16* __restrict__ Z16)
{
  extern __shared__ __align__(16) unsigned lds_u[];
  unsigned* cnt32 = lds_u;                                   // [112][33] u32
  _Float16* Adh = (_Float16*)(lds_u + 112 * kCntW);          // [112][136]
  _Float16* Hst = (_Float16*)((char*)lds_u + 45248);         // [128][136]
  float* scr = (float*)lds_u;
  __shared__ int scnt[kNPG];
  __shared__ float sdinv[kNPG];
  const int yb = blockIdx.y;
  const _Float16* H = (yb == 0) ? H0 : (yb == 1) ? H1 : H2;
  const int* srcI = (yb == 0) ? src0 : (yb == 1) ? src1 : src2;
  const int* dstI = (yb == 0) ? dst0 : (yb == 1) ? dst1 : dst2;
  const float* bias = (yb == 0) ? bias0 : bias12;
  const int epg = (yb == 0) ? kEPG : kESG;
  const int g = blockIdx.x, tid = threadIdx.x;
  const int base = g * kNPG;
  const size_t ebase = (size_t)g * epg;
  const int lane = tid & 63, wv = tid >> 6;
  const int l15 = lane & 15, lg = lane >> 4;

  for (int i = tid; i < 112 * kCntW; i += 512) cnt32[i] = 0u;
  for (int i = tid; i < 128 * 18; i += 512) {
    int c = i / 18, w = i - c * 18;
    ((unsigned*)&Hst[c * kAhS + 100])[w] = 0u;
  }
  if (tid < kNPG) scnt[tid] = 0;
  __syncthreads();
  for (int e = tid; e < epg; e += 512) {
    int s = srcI[ebase + e] - base;
    int d = dstI[ebase + e] - base;
    atomicAdd(&scnt[d], 1);
    atomicAdd(&cnt32[d * kCntW + (s >> 2)], 1u << (8 * (s & 3)));
  }
  __syncthreads();
  if (tid < kNPG) sdinv[tid] = rsqrtf((float)scnt[tid] + 1.f);
  __syncthreads();
  for (int i = tid; i < 112 * kAhS; i += 512) {
    int d = i / kAhS, s = i - d * kAhS;
    float v = 0.f;
    if (d < 100 && s < 100) {
      unsigned w = cnt32[d * kCntW + (s >> 2)];
      unsigned c = (w >> (8 * (s & 3))) & 0xFFu;
      c += (s == d) ? 1u : 0u;
      v = (float)c * sdinv[s] * sdinv[d];
    }
    Adh[i] = (_Float16)v;
  }
  if constexpr (W == 128) {
    const int c = tid & 127;
    for (int j = tid >> 7; j < 100; j += 4)
      Hst[c * kAhS + j] = H[(size_t)(base + j) * 128 + c];
  }
  __syncthreads();

  if constexpr (W == 256) {
    _Float16* OUT = (yb == 0) ? (_Float16*)OUT0 : (yb == 1) ? (_Float16*)OUT1 : (_Float16*)OUT2;
#pragma unroll
    for (int half = 0; half < 2; ++half) {
      if (half) __syncthreads();
      {
        const int c = tid & 127;
        for (int j = tid >> 7; j < 100; j += 4)
          Hst[c * kAhS + j] = H[(size_t)(base + j) * 256 + half * 128 + c];
      }
      __syncthreads();
      const int cb = wv * 16;
      const int col = half * 128 + cb + l15;
      f32x4 acc[7];
#pragma unroll
      for (int mt = 0; mt < 7; ++mt) acc[mt] = (f32x4){0.f, 0.f, 0.f, 0.f};
#pragma unroll
      for (int k0 = 0; k0 < 128; k0 += 32) {
        const int kb = k0 + lg * 8;
        half8 bF = *(const half8*)&Hst[(cb + l15) * kAhS + kb];
#pragma unroll
        for (int mt = 0; mt < 7; ++mt) {
          half8 aF = *(const half8*)&Adh[(mt * 16 + l15) * kAhS + kb];
          acc[mt] = __builtin_amdgcn_mfma_f32_16x16x32_f16(aF, bF, acc[mt], 0, 0, 0);
        }
      }
      float bv = bias[col];
#pragma unroll
      for (int mt = 0; mt < 7; ++mt)
#pragma unroll
        for (int q = 0; q < 4; ++q)
          acc[mt][q] = fmaxf(acc[mt][q] + bv, 0.f);
      float s0 = 0.f, s20 = 0.f;
#pragma unroll
      for (int mt = 0; mt < 7; ++mt)
#pragma unroll
        for (int q = 0; q < 4; ++q) {
          int row = mt * 16 + lg * 4 + q;
          if (row < 100) { float v = acc[mt][q]; s0 += v; s20 += v * v; }
        }
      s0 += __shfl_xor(s0, 16, 64);  s0 += __shfl_xor(s0, 32, 64);
      s20 += __shfl_xor(s20, 16, 64); s20 += __shfl_xor(s20, 32, 64);
      if (yb == 0) {
        if (lg == 0) {
          PST[(size_t)g * 512 + col] = s0;
          PST[(size_t)g * 512 + 256 + col] = s20;
        }
      } else {
        float m0 = s0 / 100.f, r0 = rsqrtf(s20 / 100.f - m0 * m0 + BN_EPS);
#pragma unroll
        for (int mt = 0; mt < 7; ++mt)
#pragma unroll
          for (int q = 0; q < 4; ++q)
            acc[mt][q] = (acc[mt][q] - m0) * r0;
      }
#pragma unroll
      for (int mt = 0; mt < 7; ++mt)
#pragma unroll
        for (int q = 0; q < 4; ++q) {
          int row = mt * 16 + lg * 4 + q;
          if (row < 100)
            OUT[(size_t)(base + row) * 256 + col] = (_Float16)acc[mt][q];
        }
    }
  } else {
    const int mt = wv;
    f32x4 acc[8];
#pragma unroll
    for (int nt = 0; nt < 8; ++nt) acc[nt] = (f32x4){0.f, 0.f, 0.f, 0.f};
    if (mt < 7) {
#pragma unroll
      for (int k0 = 0; k0 < 128; k0 += 32) {
        const int kb = k0 + lg * 8;
        half8 aF = *(const half8*)&Adh[(mt * 16 + l15) * kAhS + kb];
#pragma unroll
        for (int nt = 0; nt < 8; ++nt) {
          half8 bF = *(const half8*)&Hst[(nt * 16 + l15) * kAhS + kb];
          acc[nt] = __builtin_amdgcn_mfma_f32_16x16x32_f16(aF, bF, acc[nt], 0, 0, 0);
        }
      }
#pragma unroll
      for (int nt = 0; nt < 8; ++nt) {
        float bvn = bias[nt * 16 + l15];
#pragma unroll
        for (int q = 0; q < 4; ++q) acc[nt][q] += bvn;
      }
#pragma unroll
      for (int q = 0; q < 4; ++q) {
        float ss = 0.f;
#pragma unroll
        for (int nt = 0; nt < 8; ++nt) ss += acc[nt][q] * acc[nt][q];
        ss += __shfl_xor(ss, 1, 64); ss += __shfl_xor(ss, 2, 64);
        ss += __shfl_xor(ss, 4, 64); ss += __shfl_xor(ss, 8, 64);
        float inv = 1.f / fmaxf(sqrtf(ss), 1e-12f);
#pragma unroll
        for (int nt = 0; nt < 8; ++nt) acc[nt][q] *= inv;
      }
    }
    if (yb == 0) {
      float* OZ = (float*)OUT0;
      if (mt < 7) {
#pragma unroll
        for (int nt = 0; nt < 8; ++nt)
#pragma unroll
          for (int q = 0; q < 4; ++q) {
            int row = mt * 16 + lg * 4 + q;
            if (row < 100) {
              OZ[(size_t)(base + row) * 128 + nt * 16 + l15] = acc[nt][q];
              Z16[(size_t)(base + row) * 128 + nt * 16 + l15] = (_Float16)acc[nt][q];
            }
          }
      }
      float m1[8], m2[8];
#pragma unroll
      for (int nt = 0; nt < 8; ++nt) { m1[nt] = -INFINITY; m2[nt] = -INFINITY; }
      if (mt < 7) {
#pragma unroll
        for (int nt = 0; nt < 8; ++nt)
#pragma unroll
          for (int q = 0; q < 4; ++q) {
            int row = mt * 16 + lg * 4 + q;
            if (row < 100) {
              float zv = acc[nt][q];
              float nv = NOI[(size_t)(base + row) * 128 + nt * 16 + l15];
              m1[nt] = fmaxf(m1[nt], zv);
              m2[nt] = fmaxf(m2[nt], zv + nv);
            }
          }
#pragma unroll
        for (int nt = 0; nt < 8; ++nt) {
          m1[nt] = fmaxf(m1[nt], __shfl_xor(m1[nt], 16, 64));
          m1[nt] = fmaxf(m1[nt], __shfl_xor(m1[nt], 32, 64));
          m2[nt] = fmaxf(m2[nt], __shfl_xor(m2[nt], 16, 64));
          m2[nt] = fmaxf(m2[nt], __shfl_xor(m2[nt], 32, 64));
        }
      }
      __syncthreads();
      if (mt < 7 && lg == 0)
#pragma unroll
        for (int nt = 0; nt < 8; ++nt) {
          scr[wv * 128 + nt * 16 + l15] = m1[nt];
          scr[1024 + wv * 128 + nt * 16 + l15] = m2[nt];
        }
      __syncthreads();
      if (tid < 128) {
        float a = -INFINITY, b = -INFINITY;
        for (int w2 = 0; w2 < 7; ++w2) {
          a = fmaxf(a, scr[w2 * 128 + tid]);
          b = fmaxf(b, scr[1024 + w2 * 128 + tid]);
        }
        ZG[(size_t)g * 128 + tid] = a;
        ZZ[(size_t)g * 128 + tid] = a;
        ZZ[(size_t)(500 + g) * 128 + tid] = b;
      }
    } else {
      float* OP = (yb == 1) ? (float*)OUT1 : (float*)OUT2;
      float ps[8];
#pragma unroll
      for (int nt = 0; nt < 8; ++nt) ps[nt] = 0.f;
      if (mt < 7) {
#pragma unroll
        for (int nt = 0; nt < 8; ++nt)
#pragma unroll
          for (int q = 0; q < 4; ++q) {
            int row = mt * 16 + lg * 4 + q;
            if (row < 100) ps[nt] += acc[nt][q];
          }
      }
#pragma unroll
      for (int nt = 0; nt < 8; ++nt) {
        ps[nt] += __shfl_xor(ps[nt], 16, 64);
        ps[nt] += __shfl_xor(ps[nt], 32, 64);
      }
      __syncthreads();
      if (mt < 7 && lg == 0)
#pragma unroll
        for (int nt = 0; nt < 8; ++nt) scr[wv * 128 + nt * 16 + l15] = ps[nt];
      __syncthreads();
      if (tid < 128) {
        float s = 0.f;
        for (int w2 = 0; w2 < 7; ++w2) s += scr[w2 * 128 + tid];
        OP[(size_t)g * 128 + tid] = s / 100.f;
      }
    }
  }
}

// ============ BN finalize: sum 500 per-graph partials (fixed order) ============
__global__ __launch_bounds__(256)
void bn_red_k(const float* __restrict__ P, float* __restrict__ stats)
{
  const int c = threadIdx.x;
  float s = 0.f, s2 = 0.f;
  for (int b = 0; b < 500; ++b) {
    s  += P[(size_t)b * 512 + c];
    s2 += P[(size_t)b * 512 + 256 + c];
  }
  float m = s / (float)kN;
  float v = s2 / (float)kN - m * m;
  stats[512 + c] = m;
  stats[768 + c] = rsqrtf(v + BN_EPS);
}

__global__ __launch_bounds__(64)
void bn_cols_k(float* __restrict__ X, int rows, int cols)
{
  const int c = blockIdx.x, t = threadIdx.x;
  float s = 0.f, s2 = 0.f;
  for (int r = t; r < rows; r += 64) {
    float v = X[(size_t)r * cols + c];
    s += v; s2 += v * v;
  }
#pragma unroll
  for (int o = 32; o; o >>= 1) { s += __shfl_xor(s, o, 64); s2 += __shfl_xor(s2, o, 64); }
  float m = s / (float)rows;
  float var = s2 / (float)rows - m * m;
  float rinv = rsqrtf(var + BN_EPS);
  for (int r = t; r < rows; r += 64)
    X[(size_t)r * cols + c] = (X[(size_t)r * cols + c] - m) * rinv;
}

__global__ __launch_bounds__(256)
void l2n_k(const float* __restrict__ X, float* __restrict__ Y, int rows)
{
  const int w = threadIdx.x >> 6, lane = threadIdx.x & 63;
  const int row = blockIdx.x * 4 + w;
  if (row >= rows) return;
  float2 v = *(const float2*)&X[(size_t)row * kH2 + lane * 2];
  float ss = v.x * v.x + v.y * v.y;
#pragma unroll
  for (int o = 32; o; o >>= 1) ss += __shfl_xor(ss, o, 64);
  float inv = 1.f / fmaxf(sqrtf(ss), 1e-12f);
  *(float2*)&Y[(size_t)row * kH2 + lane * 2] = make_float2(v.x * inv, v.y * inv);
}

// =========================================================================
extern "C" void kernel_launch(void* const* d_in, const int* in_sizes, int n_in,
                              void* d_out, int out_size, void* d_ws, size_t ws_size,
                              hipStream_t stream)
{
  const float* x        = (const float*)d_in[0];
  const int*   srcI     = (const int*)d_in[1];
  const int*   dstI     = (const int*)d_in[2];
  const float* pos_x    = (const float*)d_in[4];
  const int*   psrc     = (const int*)d_in[5];
  const int*   pdst     = (const int*)d_in[6];
  const float* neg_x    = (const float*)d_in[8];
  const int*   nsrc     = (const int*)d_in[9];
  const int*   ndst     = (const int*)d_in[10];
  const float* target_x = (const float*)d_in[12];
  const float* noise    = (const float*)d_in[13];
  const float* W_enc1   = (const float*)d_in[14];
  const float* b_enc1   = (const float*)d_in[15];
  const float* W_enc2   = (const float*)d_in[16];
  const float* b_enc2   = (const float*)d_in[17];
  const float* W_dec1   = (const float*)d_in[18];
  const float* W_dec2   = (const float*)d_in[19];
  const float* Wn1      = (const float*)d_in[20];
  const float* bn1      = (const float*)d_in[21];
  const float* Wn2      = (const float*)d_in[22];
  const float* bn2      = (const float*)d_in[23];
  const float* Ws1      = (const float*)d_in[24];
  const float* bs1      = (const float*)d_in[25];
  const float* Wp1      = (const float*)d_in[26];
  const float* bp1      = (const float*)d_in[27];
  const float* Wp2      = (const float*)d_in[28];
  const float* bp2      = (const float*)d_in[29];

  float* out  = (float*)d_out;
  float* o_z   = out;                 // N x 128
  float* o_zg  = out + 6400000;       // 500 x 128
  float* o_xr  = out + 6464000;       // N x 128
  float* o_pos = out + 12864000;      // 500 x 128
  float* o_neg = out + 12928000;
  float* o_zgm = out + 12992000;      // o_zgm||o_zpm contiguous 1000 x 128
  float* o_tz  = out + 13120000;

  // WORKSPACE MAP — identical to r16 (audited); decoder no longer uses q0
  // as hDec (fused).
  float* ws = (float*)d_ws;
  _Float16* q0 = (_Float16*)ws;
  _Float16* q1 = (_Float16*)(ws + 6400000);
  _Float16* q2 = (_Float16*)(ws + 12800000);
  _Float16* q3 = (_Float16*)(ws + 19200000);
  _Float16* oZq = (_Float16*)o_z;      // scratch until step5
  _Float16* oXq = (_Float16*)o_xr;     // scratch until step5
  float* pstat = out + 12864000;       // consumed by bn_red before o_pos written
  _Float16* hWt = (_Float16*)(ws + 25600000);
  float* stats = ws + 25700000;
  float* zz    = ws + 22400000;
  float* t1000 = ws + 22600000;
  float* t1    = ws + 6400000;
  float* t2    = ws + 6700000;
  _Float16* z16 = q3;
  if (ws_size < (size_t)(25921024) * sizeof(float)) return;

  _Float16* WtEnc1 = hWt;
  _Float16* WtEnc2 = hWt + 32768;
  _Float16* WtDec1 = hWt + 65536;
  _Float16* WtDec2 = hWt + 98304;
  _Float16* WtS1   = hWt + 131072;

  (void)hipFuncSetAttribute((const void*)gcn_agg3_k<256>,
      hipFuncAttributeMaxDynamicSharedMemorySize, kAggLds);
  (void)hipFuncSetAttribute((const void*)gcn_agg3_k<128>,
      hipFuncAttributeMaxDynamicSharedMemorySize, kAggLds);

  const dim3 gB3(782, 2, 3);
  const dim3 gC3(782, 1, 3);
  auto gg = [](int M, int Nc) {
    return dim3((unsigned)((M + 127) / 128), (unsigned)(Nc / 64), 1);
  };

  // 1. weight prep
  wprep_k<<<640, 256, 0, stream>>>(W_enc1, W_enc2, W_dec1, W_dec2, Ws1, hWt);

  // 2. layer-1 GEMMs, 3-wide
  gemm_direct_k<0, 0, 128, 256, float, _Float16><<<gB3, 256, 0, stream>>>(
      x, pos_x, neg_x, WtEnc1, WtS1, WtS1, nullptr, q0, q1, q2, kN);

  // 3. agg256 x3 (staged B): Q0..Q2 -> Q3, oZq, oXq (+pstat for main)
  gcn_agg3_k<256><<<dim3(kB, 3), 512, kAggLds, stream>>>(
      q0, q1, q2, srcI, psrc, nsrc, dstI, pdst, ndst, b_enc1, bs1,
      q3, oZq, oXq, nullptr, pstat, nullptr, nullptr, nullptr);

  // 4. BN finalize
  bn_red_k<<<1, 256, 0, stream>>>(pstat, stats);

  // 5. layer-2 GEMMs, 3-wide (BN transform only z==0)
  gemm_direct_k<0, 2, 256, 128, _Float16, _Float16><<<gC3, 256, 0, stream>>>(
      q3, oZq, oXq, WtEnc2, WtEnc2, WtEnc2, stats + 512, q0, q1, q2, kN);

  // 6. agg128 x3: Q0..Q2 -> o_z(+z16), o_pos, o_neg; ZG/ZZ for main
  gcn_agg3_k<128><<<dim3(kB, 3), 512, kAggLds, stream>>>(
      q0, q1, q2, srcI, psrc, nsrc, dstI, pdst, ndst, b_enc2, b_enc2,
      o_z, o_pos, o_neg, noise, nullptr, o_zg, zz, z16);

  // 7. fused decoder: z16(Q3) -> o_xr (one launch, no hDec round trip)
  dec_fused_k<<<782, 512, 0, stream>>>(z16, WtDec1, WtDec2, o_xr, kN);

  // 8-9. merged projection heads
  gemm_k<1><<<gg(1000, kH2), 256, 0, stream>>>(zz, Wp1, bp1, t1000, 1000, kH2, kH2);
  gemm_k<0><<<gg(1000, kH2), 256, 0, stream>>>(t1000, Wp2, bp2, o_zgm, 1000, kH2, kH2);

  // 10-13. target node encoder
  gemm_k<1><<<gg(kB, kH1), 256, 0, stream>>>(target_x, Wn1, bn1, t1, kB, kF0, kH1);
  bn_cols_k<<<256, 64, 0, stream>>>(t1, kB, kH1);
  gemm_k<0><<<gg(kB, kH2), 256, 0, stream>>>(t1, Wn2, bn2, t2, kB, kH1, kH2);
  l2n_k<<<125, 256, 0, stream>>>(t2, o_tz, kB);

  (void)in_sizes; (void)n_in; (void)out_size;
}

// Round 18
// 338.943 us; speedup vs baseline: 1.1140x; 1.0420x over previous
//
#include <hip/hip_runtime.h>
#include <math.h>

static constexpr int kN   = 50000;
static constexpr int kB   = 500;
static constexpr int kNPG = 100;
static constexpr int kEPG = 1600;
static constexpr int kESG = 800;
static constexpr int kF0  = 128;
static constexpr int kH1  = 256;
static constexpr int kH2  = 128;
#define BN_EPS 1e-5f

typedef _Float16 half8 __attribute__((ext_vector_type(8)));
typedef __attribute__((ext_vector_type(4))) float f32x4;

static constexpr int kCntW = 33;
static constexpr int kAhS  = 136;     // Adh / hT / hT2 stride (fp16)
static constexpr int kH2S  = 264;     // h2 stride (fp16)
// enc1 LDS (bytes): Adh[112][136] @0 (30464) | hT[256][136] @30464 (69632)
//  | h2[112][264] @100096 (59136). cnt32 overlays hT pre-GEMM1; hT2[128][136]
//  overlays hT post-agg256; scr overlays Adh post-agg128. Total 159232.
static constexpr unsigned kLds1 = 159232;
// enc2 LDS: Adh 30464 | hT2[128][136] @30464 (34816) (cnt overlays hT2). 65280.
static constexpr unsigned kLds2 = 65280;

// ============ weight prep: W[K][Nc] f32 -> Wt[(kg*Nc + c)*8 + e] fp16 ============
__global__ __launch_bounds__(256)
void wprep_k(const float* __restrict__ s0, const float* __restrict__ s1,
             const float* __restrict__ s2, const float* __restrict__ s3,
             const float* __restrict__ s4, _Float16* __restrict__ d)
{
  int seg = blockIdx.x >> 7;
  int idx = (blockIdx.x & 127) * 256 + threadIdx.x;
  const float* S; int Nc;
  switch (seg) {
    case 0: S = s0; Nc = 256; break;
    case 1: S = s1; Nc = 128; break;
    case 2: S = s2; Nc = 256; break;
    case 3: S = s3; Nc = 128; break;
    default: S = s4; Nc = 256; break;
  }
  int e = idx & 7, t = idx >> 3;
  int c = t % Nc, kg = t / Nc;
  d[seg * 32768 + idx] = (_Float16)S[(size_t)(kg * 8 + e) * Nc + c];
}

// ================= phase-1 fused encoder (per-graph blocks) =================
// blockIdx.y: 0=main (GEMM1+agg256+STATS -> hB global, stops), 1=pos, 2=neg
// (full chain GEMM1+agg256+segBN -> GEMM2+agg128+l2n+pool -> OP).
__global__ __launch_bounds__(512)
void enc1_k(const float* __restrict__ x0, const float* __restrict__ x1,
            const float* __restrict__ x2,
            const int* __restrict__ src0, const int* __restrict__ src1,
            const int* __restrict__ src2,
            const int* __restrict__ dst0, const int* __restrict__ dst1,
            const int* __restrict__ dst2,
            const _Float16* __restrict__ Wt1m, const _Float16* __restrict__ Wt1s,
            const _Float16* __restrict__ Wt2,
            const float* __restrict__ b1m, const float* __restrict__ b1s,
            const float* __restrict__ b2,
            _Float16* __restrict__ hB, float* __restrict__ PST,
            float* __restrict__ OP1, float* __restrict__ OP2)
{
  extern __shared__ __align__(16) char lds_c[];
  _Float16* Adh = (_Float16*)lds_c;                 // [112][136]
  _Float16* hT  = (_Float16*)(lds_c + 30464);       // [256][136]
  _Float16* h2  = (_Float16*)(lds_c + 100096);      // [112][264]
  unsigned* cnt32 = (unsigned*)(lds_c + 30464);     // overlay (build only)
  _Float16* hT2 = (_Float16*)(lds_c + 30464);       // overlay (stage 3+)
  float* scr = (float*)lds_c;                       // overlay (pool epilogue)
  __shared__ int scnt[kNPG];
  __shared__ float sdinv[kNPG];
  const int yb = blockIdx.y;
  const float* X = (yb == 0) ? x0 : (yb == 1) ? x1 : x2;
  const int* srcI = (yb == 0) ? src0 : (yb == 1) ? src1 : src2;
  const int* dstI = (yb == 0) ? dst0 : (yb == 1) ? dst1 : dst2;
  const _Float16* W1 = (yb == 0) ? Wt1m : Wt1s;
  const float* bias1 = (yb == 0) ? b1m : b1s;
  const int epg = (yb == 0) ? kEPG : kESG;
  const int g = blockIdx.x, tid = threadIdx.x;
  const int base = g * kNPG;
  const size_t ebase = (size_t)g * epg;
  const int lane = tid & 63, wv = tid >> 6;
  const int l15 = lane & 15, lg = lane >> 4;

  // ---- build adjacency (deterministic integer counts)
  for (int i = tid; i < 112 * kCntW; i += 512) cnt32[i] = 0u;
  if (tid < kNPG) scnt[tid] = 0;
  __syncthreads();
  for (int e = tid; e < epg; e += 512) {
    int s = srcI[ebase + e] - base;
    int d = dstI[ebase + e] - base;
    atomicAdd(&scnt[d], 1);
    atomicAdd(&cnt32[d * kCntW + (s >> 2)], 1u << (8 * (s & 3)));
  }
  __syncthreads();
  if (tid < kNPG) sdinv[tid] = rsqrtf((float)scnt[tid] + 1.f);
  __syncthreads();
  for (int i = tid; i < 112 * kAhS; i += 512) {
    int d = i / kAhS, s = i - d * kAhS;
    float v = 0.f;
    if (d < 100 && s < 100) {
      unsigned w = cnt32[d * kCntW + (s >> 2)];
      unsigned c = (w >> (8 * (s & 3))) & 0xFFu;
      c += (s == d) ? 1u : 0u;
      v = (float)c * sdinv[s] * sdinv[d];
    }
    Adh[i] = (_Float16)v;
  }
  __syncthreads();   // cnt dead; hT region writable

  // ---- stage 1: GEMM1 (M=128 rows incl clamp-junk, N=256, K=128) -> hT^T
  {
    f32x4 a1[8][2];
#pragma unroll
    for (int mt = 0; mt < 8; ++mt) {
      a1[mt][0] = (f32x4){0.f, 0.f, 0.f, 0.f};
      a1[mt][1] = (f32x4){0.f, 0.f, 0.f, 0.f};
    }
    int rows[8];
#pragma unroll
    for (int mt = 0; mt < 8; ++mt) rows[mt] = min(base + mt * 16 + l15, kN - 1);
    const int bc0 = wv * 32 + l15;
#pragma unroll
    for (int ks = 0; ks < 4; ++ks) {
      const int kb = ks * 32 + lg * 8;
      half8 bF[2];
#pragma unroll
      for (int t = 0; t < 2; ++t)
        bF[t] = *(const half8*)&W1[((size_t)(ks * 4 + lg) * 256 + bc0 + t * 16) * 8];
#pragma unroll
      for (int mt = 0; mt < 8; ++mt) {
        const float* ap = X + (size_t)rows[mt] * 128 + kb;
        float4 u0 = *(const float4*)ap, u1 = *(const float4*)(ap + 4);
        half8 aF;
        aF[0] = (_Float16)u0.x; aF[1] = (_Float16)u0.y;
        aF[2] = (_Float16)u0.z; aF[3] = (_Float16)u0.w;
        aF[4] = (_Float16)u1.x; aF[5] = (_Float16)u1.y;
        aF[6] = (_Float16)u1.z; aF[7] = (_Float16)u1.w;
#pragma unroll
        for (int t = 0; t < 2; ++t)
          a1[mt][t] = __builtin_amdgcn_mfma_f32_16x16x32_f16(aF, bF[t], a1[mt][t], 0, 0, 0);
      }
    }
#pragma unroll
    for (int mt = 0; mt < 8; ++mt)
#pragma unroll
      for (int t = 0; t < 2; ++t)
#pragma unroll
        for (int q = 0; q < 4; ++q) {
          int col = wv * 32 + t * 16 + l15;
          int j = mt * 16 + lg * 4 + q;
          hT[col * kAhS + j] = (_Float16)a1[mt][t][q];
        }
  }
  __syncthreads();

  // ---- stage 2: agg256 (M=112, cols wv*32..+31) + bias + relu + stats/segBN
  {
    f32x4 a2[7][2];
#pragma unroll
    for (int mt = 0; mt < 7; ++mt) {
      a2[mt][0] = (f32x4){0.f, 0.f, 0.f, 0.f};
      a2[mt][1] = (f32x4){0.f, 0.f, 0.f, 0.f};
    }
#pragma unroll
    for (int ks = 0; ks < 4; ++ks) {
      const int kb = ks * 32 + lg * 8;
      half8 bF[2];
#pragma unroll
      for (int t = 0; t < 2; ++t)
        bF[t] = *(const half8*)&hT[(wv * 32 + t * 16 + l15) * kAhS + kb];
#pragma unroll
      for (int mt = 0; mt < 7; ++mt) {
        half8 aF = *(const half8*)&Adh[(mt * 16 + l15) * kAhS + kb];
        a2[mt][0] = __builtin_amdgcn_mfma_f32_16x16x32_f16(aF, bF[0], a2[mt][0], 0, 0, 0);
        a2[mt][1] = __builtin_amdgcn_mfma_f32_16x16x32_f16(aF, bF[1], a2[mt][1], 0, 0, 0);
      }
    }
    float bv0 = bias1[wv * 32 + l15];
    float bv1 = bias1[wv * 32 + 16 + l15];
#pragma unroll
    for (int mt = 0; mt < 7; ++mt)
#pragma unroll
      for (int q = 0; q < 4; ++q) {
        a2[mt][0][q] = fmaxf(a2[mt][0][q] + bv0, 0.f);
        a2[mt][1][q] = fmaxf(a2[mt][1][q] + bv1, 0.f);
      }
    float s0 = 0.f, s20 = 0.f, s1 = 0.f, s21 = 0.f;
#pragma unroll
    for (int mt = 0; mt < 7; ++mt)
#pragma unroll
      for (int q = 0; q < 4; ++q) {
        int row = mt * 16 + lg * 4 + q;
        if (row < 100) {
          float v0 = a2[mt][0][q], v1 = a2[mt][1][q];
          s0 += v0; s20 += v0 * v0; s1 += v1; s21 += v1 * v1;
        }
      }
    s0 += __shfl_xor(s0, 16, 64);  s0 += __shfl_xor(s0, 32, 64);
    s20 += __shfl_xor(s20, 16, 64); s20 += __shfl_xor(s20, 32, 64);
    s1 += __shfl_xor(s1, 16, 64);  s1 += __shfl_xor(s1, 32, 64);
    s21 += __shfl_xor(s21, 16, 64); s21 += __shfl_xor(s21, 32, 64);
    if (yb == 0) {
      if (lg == 0) {
        PST[(size_t)g * 512 + wv * 32 + l15] = s0;
        PST[(size_t)g * 512 + 256 + wv * 32 + l15] = s20;
        PST[(size_t)g * 512 + wv * 32 + 16 + l15] = s1;
        PST[(size_t)g * 512 + 256 + wv * 32 + 16 + l15] = s21;
      }
#pragma unroll
      for (int mt = 0; mt < 7; ++mt)
#pragma unroll
        for (int q = 0; q < 4; ++q) {
          int row = mt * 16 + lg * 4 + q;
          if (row < 100) {
            hB[(size_t)(base + row) * 256 + wv * 32 + l15] = (_Float16)a2[mt][0][q];
            hB[(size_t)(base + row) * 256 + wv * 32 + 16 + l15] = (_Float16)a2[mt][1][q];
          }
        }
    } else {
      float m0 = s0 / 100.f, r0 = rsqrtf(s20 / 100.f - m0 * m0 + BN_EPS);
      float m1 = s1 / 100.f, r1 = rsqrtf(s21 / 100.f - m1 * m1 + BN_EPS);
#pragma unroll
      for (int mt = 0; mt < 7; ++mt)
#pragma unroll
        for (int q = 0; q < 4; ++q) {
          int row = mt * 16 + lg * 4 + q;
          h2[row * kH2S + wv * 32 + l15] = (_Float16)((a2[mt][0][q] - m0) * r0);
          h2[row * kH2S + wv * 32 + 16 + l15] = (_Float16)((a2[mt][1][q] - m1) * r1);
        }
    }
  }
  if (yb == 0) return;   // block-uniform exit (main phase-A done)

  __syncthreads();   // h2 complete; hT reads done -> hT2 region writable

  // ---- stage 3: GEMM2 (M=112 via wave=mt, N=128, K=256) -> hT2^T
  {
    for (int i = tid; i < 128 * 16; i += 512) {          // zero pad rows 112..127
      int c = i >> 4, j = 112 + (i & 15);
      hT2[c * kAhS + j] = (_Float16)0.f;
    }
    const int mt = wv;
    f32x4 a3[8];
#pragma unroll
    for (int nt = 0; nt < 8; ++nt) a3[nt] = (f32x4){0.f, 0.f, 0.f, 0.f};
    if (mt < 7) {
#pragma unroll
      for (int ks = 0; ks < 8; ++ks) {
        const int kb = ks * 32 + lg * 8;
        half8 aF = *(const half8*)&h2[(mt * 16 + l15) * kH2S + kb];
#pragma unroll
        for (int nt = 0; nt < 8; ++nt) {
          half8 bF = *(const half8*)&Wt2[((size_t)(ks * 4 + lg) * 128 + nt * 16 + l15) * 8];
          a3[nt] = __builtin_amdgcn_mfma_f32_16x16x32_f16(aF, bF, a3[nt], 0, 0, 0);
        }
      }
#pragma unroll
      for (int nt = 0; nt < 8; ++nt)
#pragma unroll
        for (int q = 0; q < 4; ++q) {
          int col = nt * 16 + l15;
          int j = mt * 16 + lg * 4 + q;
          hT2[col * kAhS + j] = (_Float16)a3[nt][q];
        }
    }
  }
  __syncthreads();

  // ---- stage 4: agg128 + bias + l2norm + mean-pool
  {
    const int mt = wv;
    f32x4 a4[8];
#pragma unroll
    for (int nt = 0; nt < 8; ++nt) a4[nt] = (f32x4){0.f, 0.f, 0.f, 0.f};
    if (mt < 7) {
#pragma unroll
      for (int ks = 0; ks < 4; ++ks) {
        const int kb = ks * 32 + lg * 8;
        half8 aF = *(const half8*)&Adh[(mt * 16 + l15) * kAhS + kb];
#pragma unroll
        for (int nt = 0; nt < 8; ++nt) {
          half8 bF = *(const half8*)&hT2[(nt * 16 + l15) * kAhS + kb];
          a4[nt] = __builtin_amdgcn_mfma_f32_16x16x32_f16(aF, bF, a4[nt], 0, 0, 0);
        }
      }
#pragma unroll
      for (int nt = 0; nt < 8; ++nt) {
        float bvn = b2[nt * 16 + l15];
#pragma unroll
        for (int q = 0; q < 4; ++q) a4[nt][q] += bvn;
      }
#pragma unroll
      for (int q = 0; q < 4; ++q) {
        float ss = 0.f;
#pragma unroll
        for (int nt = 0; nt < 8; ++nt) ss += a4[nt][q] * a4[nt][q];
        ss += __shfl_xor(ss, 1, 64); ss += __shfl_xor(ss, 2, 64);
        ss += __shfl_xor(ss, 4, 64); ss += __shfl_xor(ss, 8, 64);
        float inv = 1.f / fmaxf(sqrtf(ss), 1e-12f);
#pragma unroll
        for (int nt = 0; nt < 8; ++nt) a4[nt][q] *= inv;
      }
    }
    float ps[8];
#pragma unroll
    for (int nt = 0; nt < 8; ++nt) ps[nt] = 0.f;
    if (mt < 7) {
#pragma unroll
      for (int nt = 0; nt < 8; ++nt)
#pragma unroll
        for (int q = 0; q < 4; ++q) {
          int row = mt * 16 + lg * 4 + q;
          if (row < 100) ps[nt] += a4[nt][q];
        }
    }
#pragma unroll
    for (int nt = 0; nt < 8; ++nt) {
      ps[nt] += __shfl_xor(ps[nt], 16, 64);
      ps[nt] += __shfl_xor(ps[nt], 32, 64);
    }
    __syncthreads();                  // Adh dead -> scr
    if (mt < 7 && lg == 0)
#pragma unroll
      for (int nt = 0; nt < 8; ++nt) scr[wv * 128 + nt * 16 + l15] = ps[nt];
    __syncthreads();
    if (tid < 128) {
      float s = 0.f;
      for (int w2 = 0; w2 < 7; ++w2) s += scr[w2 * 128 + tid];
      float* OP = (yb == 1) ? OP1 : OP2;
      OP[(size_t)g * 128 + tid] = s / 100.f;
    }
  }
}

// ================= phase-2 fused encoder (main): hB -> BN -> GEMM2 -> agg128 =================
__global__ __launch_bounds__(512)
void enc2_k(const _Float16* __restrict__ hB, const float* __restrict__ tr,
            const _Float16* __restrict__ Wt2, const float* __restrict__ b2,
            const int* __restrict__ srcI, const int* __restrict__ dstI,
            const float* __restrict__ NOI,
            float* __restrict__ OZ, _Float16* __restrict__ Z16,
            float* __restrict__ ZG, float* __restrict__ ZZ)
{
  extern __shared__ __align__(16) char lds_c[];
  _Float16* Adh = (_Float16*)lds_c;                 // [112][136]
  _Float16* hT2 = (_Float16*)(lds_c + 30464);       // [128][136]
  unsigned* cnt32 = (unsigned*)(lds_c + 30464);     // overlay (build only)
  float* scr = (float*)lds_c;                       // overlay (epilogue)
  __shared__ int scnt[kNPG];
  __shared__ float sdinv[kNPG];
  const int g = blockIdx.x, tid = threadIdx.x;
  const int base = g * kNPG;
  const size_t ebase = (size_t)g * kEPG;
  const int lane = tid & 63, wv = tid >> 6;
  const int l15 = lane & 15, lg = lane >> 4;

  for (int i = tid; i < 112 * kCntW; i += 512) cnt32[i] = 0u;
  if (tid < kNPG) scnt[tid] = 0;
  __syncthreads();
  for (int e = tid; e < kEPG; e += 512) {
    int s = srcI[ebase + e] - base;
    int d = dstI[ebase + e] - base;
    atomicAdd(&scnt[d], 1);
    atomicAdd(&cnt32[d * kCntW + (s >> 2)], 1u << (8 * (s & 3)));
  }
  __syncthreads();
  if (tid < kNPG) sdinv[tid] = rsqrtf((float)scnt[tid] + 1.f);
  __syncthreads();
  for (int i = tid; i < 112 * kAhS; i += 512) {
    int d = i / kAhS, s = i - d * kAhS;
    float v = 0.f;
    if (d < 100 && s < 100) {
      unsigned w = cnt32[d * kCntW + (s >> 2)];
      unsigned c = (w >> (8 * (s & 3))) & 0xFFu;
      c += (s == d) ? 1u : 0u;
      v = (float)c * sdinv[s] * sdinv[d];
    }
    Adh[i] = (_Float16)v;
  }
  __syncthreads();   // cnt dead -> hT2 writable

  // GEMM2 from global hB with BN transform (M=128 via wave=mt, all finite)
  {
    const int mt = wv;                 // 0..7
    const int r = min(base + mt * 16 + l15, kN - 1);
    f32x4 a3[8];
#pragma unroll
    for (int nt = 0; nt < 8; ++nt) a3[nt] = (f32x4){0.f, 0.f, 0.f, 0.f};
#pragma unroll
    for (int ks = 0; ks < 8; ++ks) {
      const int kb = ks * 32 + lg * 8;
      half8 h = *(const half8*)&hB[(size_t)r * 256 + kb];
      half8 aF;
#pragma unroll
      for (int j = 0; j < 8; ++j)
        aF[j] = (_Float16)(((float)h[j] - tr[kb + j]) * tr[256 + kb + j]);
#pragma unroll
      for (int nt = 0; nt < 8; ++nt) {
        half8 bF = *(const half8*)&Wt2[((size_t)(ks * 4 + lg) * 128 + nt * 16 + l15) * 8];
        a3[nt] = __builtin_amdgcn_mfma_f32_16x16x32_f16(aF, bF, a3[nt], 0, 0, 0);
      }
    }
#pragma unroll
    for (int nt = 0; nt < 8; ++nt)
#pragma unroll
      for (int q = 0; q < 4; ++q) {
        int col = nt * 16 + l15;
        int j = mt * 16 + lg * 4 + q;
        hT2[col * kAhS + j] = (_Float16)a3[nt][q];
      }
  }
  __syncthreads();

  // agg128 + bias + l2norm + z/z16/maxp epilogues
  {
    const int mt = wv;
    f32x4 a4[8];
#pragma unroll
    for (int nt = 0; nt < 8; ++nt) a4[nt] = (f32x4){0.f, 0.f, 0.f, 0.f};
    if (mt < 7) {
#pragma unroll
      for (int ks = 0; ks < 4; ++ks) {
        const int kb = ks * 32 + lg * 8;
        half8 aF = *(const half8*)&Adh[(mt * 16 + l15) * kAhS + kb];
#pragma unroll
        for (int nt = 0; nt < 8; ++nt) {
          half8 bF = *(const half8*)&hT2[(nt * 16 + l15) * kAhS + kb];
          a4[nt] = __builtin_amdgcn_mfma_f32_16x16x32_f16(aF, bF, a4[nt], 0, 0, 0);
        }
      }
#pragma unroll
      for (int nt = 0; nt < 8; ++nt) {
        float bvn = b2[nt * 16 + l15];
#pragma unroll
        for (int q = 0; q < 4; ++q) a4[nt][q] += bvn;
      }
#pragma unroll
      for (int q = 0; q < 4; ++q) {
        float ss = 0.f;
#pragma unroll
        for (int nt = 0; nt < 8; ++nt) ss += a4[nt][q] * a4[nt][q];
        ss += __shfl_xor(ss, 1, 64); ss += __shfl_xor(ss, 2, 64);
        ss += __shfl_xor(ss, 4, 64); ss += __shfl_xor(ss, 8, 64);
        float inv = 1.f / fmaxf(sqrtf(ss), 1e-12f);
#pragma unroll
        for (int nt = 0; nt < 8; ++nt) a4[nt][q] *= inv;
      }
      // per-node z + z16
#pragma unroll
      for (int nt = 0; nt < 8; ++nt)
#pragma unroll
        for (int q = 0; q < 4; ++q) {
          int row = mt * 16 + lg * 4 + q;
          if (row < 100) {
            OZ[(size_t)(base + row) * 128 + nt * 16 + l15] = a4[nt][q];
            Z16[(size_t)(base + row) * 128 + nt * 16 + l15] = (_Float16)a4[nt][q];
          }
        }
    }
    // col-max of z and z+noise
    float m1[8], m2[8];
#pragma unroll
    for (int nt = 0; nt < 8; ++nt) { m1[nt] = -INFINITY; m2[nt] = -INFINITY; }
    if (mt < 7) {
#pragma unroll
      for (int nt = 0; nt < 8; ++nt)
#pragma unroll
        for (int q = 0; q < 4; ++q) {
          int row = mt * 16 + lg * 4 + q;
          if (row < 100) {
            float zv = a4[nt][q];
            float nv = NOI[(size_t)(base + row) * 128 + nt * 16 + l15];
            m1[nt] = fmaxf(m1[nt], zv);
            m2[nt] = fmaxf(m2[nt], zv + nv);
          }
        }
#pragma unroll
      for (int nt = 0; nt < 8; ++nt) {
        m1[nt] = fmaxf(m1[nt], __shfl_xor(m1[nt], 16, 64));
        m1[nt] = fmaxf(m1[nt], __shfl_xor(m1[nt], 32, 64));
        m2[nt] = fmaxf(m2[nt], __shfl_xor(m2[nt], 16, 64));
        m2[nt] = fmaxf(m2[nt], __shfl_xor(m2[nt], 32, 64));
      }
    }
    __syncthreads();                  // Adh dead -> scr
    if (mt < 7 && lg == 0)
#pragma unroll
      for (int nt = 0; nt < 8; ++nt) {
        scr[wv * 128 + nt * 16 + l15] = m1[nt];
        scr[1024 + wv * 128 + nt * 16 + l15] = m2[nt];
      }
    __syncthreads();
    if (tid < 128) {
      float a = -INFINITY, b = -INFINITY;
      for (int w2 = 0; w2 < 7; ++w2) {
        a = fmaxf(a, scr[w2 * 128 + tid]);
        b = fmaxf(b, scr[1024 + w2 * 128 + tid]);
      }
      ZG[(size_t)g * 128 + tid] = a;
      ZZ[(size_t)g * 128 + tid] = a;
      ZZ[(size_t)(500 + g) * 128 + tid] = b;
    }
  }
}

// ================= fused decoder: o_xr = sigmoid(relu(z16@W1)@W2) =================
__global__ __launch_bounds__(512)
void dec_fused_k(const _Float16* __restrict__ Z, const _Float16* __restrict__ Wt1,
                 const _Float16* __restrict__ Wt2, float* __restrict__ XR, int M)
{
  __shared__ alignas(16) _Float16 Hrm[64][264];
  const int tid = threadIdx.x;
  const int lane = tid & 63;
  const int l15 = lane & 15, lg = lane >> 4;
  const int wave = tid >> 6;
  const int wm = wave >> 2;
  const int wn = wave & 3;
  const int bm = blockIdx.x * 64;

  f32x4 acc[2][4];
#pragma unroll
  for (int m = 0; m < 2; ++m)
#pragma unroll
    for (int n = 0; n < 4; ++n) acc[m][n] = (f32x4){0.f, 0.f, 0.f, 0.f};
  int arow[2];
#pragma unroll
  for (int m = 0; m < 2; ++m)
    arow[m] = min(bm + wm * 32 + m * 16 + l15, M - 1);
  const int bcol = wn * 64 + l15;
#pragma unroll
  for (int ks = 0; ks < 4; ++ks) {
    const int kb = ks * 32 + lg * 8;
    half8 bF[4];
#pragma unroll
    for (int n = 0; n < 4; ++n)
      bF[n] = *(const half8*)&Wt1[((size_t)(ks * 4 + lg) * 256 + bcol + n * 16) * 8];
    half8 aF[2];
#pragma unroll
    for (int m = 0; m < 2; ++m)
      aF[m] = *(const half8*)&Z[(size_t)arow[m] * 128 + kb];
#pragma unroll
    for (int m = 0; m < 2; ++m)
#pragma unroll
      for (int n = 0; n < 4; ++n)
        acc[m][n] = __builtin_amdgcn_mfma_f32_16x16x32_f16(aF[m], bF[n], acc[m][n], 0, 0, 0);
  }
#pragma unroll
  for (int m = 0; m < 2; ++m)
#pragma unroll
    for (int q = 0; q < 4; ++q) {
      int lrow = wm * 32 + m * 16 + lg * 4 + q;
#pragma unroll
      for (int n = 0; n < 4; ++n)
        Hrm[lrow][wn * 64 + n * 16 + l15] = (_Float16)fmaxf(acc[m][n][q], 0.f);
    }
  __syncthreads();

  const int wm2 = wave & 1, wn2 = wave >> 1;
  f32x4 acc2[2][2];
#pragma unroll
  for (int m = 0; m < 2; ++m)
#pragma unroll
    for (int n = 0; n < 2; ++n) acc2[m][n] = (f32x4){0.f, 0.f, 0.f, 0.f};
#pragma unroll
  for (int ks = 0; ks < 8; ++ks) {
    const int kb = ks * 32 + lg * 8;
    half8 aF[2];
#pragma unroll
    for (int m = 0; m < 2; ++m)
      aF[m] = *(const half8*)&Hrm[wm2 * 32 + m * 16 + l15][kb];
    half8 bF[2];
#pragma unroll
    for (int n = 0; n < 2; ++n)
      bF[n] = *(const half8*)&Wt2[((size_t)(ks * 4 + lg) * 128 + wn2 * 32 + n * 16 + l15) * 8];
#pragma unroll
    for (int m = 0; m < 2; ++m)
#pragma unroll
      for (int n = 0; n < 2; ++n)
        acc2[m][n] = __builtin_amdgcn_mfma_f32_16x16x32_f16(aF[m], bF[n], acc2[m][n], 0, 0, 0);
  }
#pragma unroll
  for (int m = 0; m < 2; ++m)
#pragma unroll
    for (int q = 0; q < 4; ++q) {
      int row = bm + wm2 * 32 + m * 16 + lg * 4 + q;
      if (row >= M) continue;
#pragma unroll
      for (int n = 0; n < 2; ++n) {
        float v = acc2[m][n][q];
        XR[(size_t)row * 128 + wn2 * 32 + n * 16 + l15] = 1.f / (1.f + expf(-v));
      }
    }
}

// ======================= small-M tiled f32 GEMM (M<=1000 paths) =======================
template<int ACT>
__global__ __launch_bounds__(256)
void gemm_k(const float* __restrict__ A, const float* __restrict__ W,
            const float* __restrict__ bias, float* __restrict__ C,
            int M, int K, int Nc)
{
  __shared__ float As[32][136];
  __shared__ float Ws[32][68];
  const int tid = threadIdx.x;
  const int bm = blockIdx.x * 128;
  const int bn = blockIdx.y * 64;
  const int tm = (tid & 15) * 8;
  const int tn = (tid >> 4) * 4;
  float acc[8][4];
#pragma unroll
  for (int i = 0; i < 8; ++i)
#pragma unroll
    for (int j = 0; j < 4; ++j) acc[i][j] = 0.f;

  for (int k0 = 0; k0 < K; k0 += 32) {
#pragma unroll
    for (int l = 0; l < 4; ++l) {
      int idx = tid + l * 256;
      int r = idx >> 3;
      int kq = (idx & 7) << 2;
      int gr = bm + r;
      float4 v = make_float4(0.f, 0.f, 0.f, 0.f);
      if (gr < M) v = *(const float4*)&A[(size_t)gr * K + k0 + kq];
      As[kq + 0][r] = v.x; As[kq + 1][r] = v.y;
      As[kq + 2][r] = v.z; As[kq + 3][r] = v.w;
    }
#pragma unroll
    for (int l = 0; l < 2; ++l) {
      int idx = tid + l * 256;
      int r = idx >> 4;
      int nq = (idx & 15) << 2;
      *(float4*)&Ws[r][nq] = *(const float4*)&W[(size_t)(k0 + r) * Nc + bn + nq];
    }
    __syncthreads();
#pragma unroll
    for (int kk = 0; kk < 32; ++kk) {
      float4 a0 = *(float4*)&As[kk][tm];
      float4 a1 = *(float4*)&As[kk][tm + 4];
      float4 w4 = *(float4*)&Ws[kk][tn];
      float am[8] = {a0.x, a0.y, a0.z, a0.w, a1.x, a1.y, a1.z, a1.w};
      float wn4[4] = {w4.x, w4.y, w4.z, w4.w};
#pragma unroll
      for (int i = 0; i < 8; ++i)
#pragma unroll
        for (int j = 0; j < 4; ++j) acc[i][j] += am[i] * wn4[j];
    }
    __syncthreads();
  }
  float4 bv = make_float4(0.f, 0.f, 0.f, 0.f);
  if (bias) bv = *(const float4*)&bias[bn + tn];
#pragma unroll
  for (int i = 0; i < 8; ++i) {
    int row = bm + tm + i;
    if (row >= M) break;
    float o0 = acc[i][0] + bv.x, o1 = acc[i][1] + bv.y;
    float o2 = acc[i][2] + bv.z, o3 = acc[i][3] + bv.w;
    if (ACT == 1) {
      o0 = fmaxf(o0, 0.f); o1 = fmaxf(o1, 0.f);
      o2 = fmaxf(o2, 0.f); o3 = fmaxf(o3, 0.f);
    } else if (ACT == 2) {
      o0 = 1.f / (1.f + expf(-o0)); o1 = 1.f / (1.f + expf(-o1));
      o2 = 1.f / (1.f + expf(-o2)); o3 = 1.f / (1.f + expf(-o3));
    }
    *(float4*)&C[(size_t)row * Nc + bn + tn] = make_float4(o0, o1, o2, o3);
  }
}

// ============ BN finalize: sum 500 per-graph partials (fixed order) ============
__global__ __launch_bounds__(256)
void bn_red_k(const float* __restrict__ P, float* __restrict__ stats)
{
  const int c = threadIdx.x;
  float s = 0.f, s2 = 0.f;
  for (int b = 0; b < 500; ++b) {
    s  += P[(size_t)b * 512 + c];
    s2 += P[(size_t)b * 512 + 256 + c];
  }
  float m = s / (float)kN;
  float v = s2 / (float)kN - m * m;
  stats[512 + c] = m;
  stats[768 + c] = rsqrtf(v + BN_EPS);
}

__global__ __launch_bounds__(64)
void bn_cols_k(float* __restrict__ X, int rows, int cols)
{
  const int c = blockIdx.x, t = threadIdx.x;
  float s = 0.f, s2 = 0.f;
  for (int r = t; r < rows; r += 64) {
    float v = X[(size_t)r * cols + c];
    s += v; s2 += v * v;
  }
#pragma unroll
  for (int o = 32; o; o >>= 1) { s += __shfl_xor(s, o, 64); s2 += __shfl_xor(s2, o, 64); }
  float m = s / (float)rows;
  float var = s2 / (float)rows - m * m;
  float rinv = rsqrtf(var + BN_EPS);
  for (int r = t; r < rows; r += 64)
    X[(size_t)r * cols + c] = (X[(size_t)r * cols + c] - m) * rinv;
}

__global__ __launch_bounds__(256)
void l2n_k(const float* __restrict__ X, float* __restrict__ Y, int rows)
{
  const int w = threadIdx.x >> 6, lane = threadIdx.x & 63;
  const int row = blockIdx.x * 4 + w;
  if (row >= rows) return;
  float2 v = *(const float2*)&X[(size_t)row * kH2 + lane * 2];
  float ss = v.x * v.x + v.y * v.y;
#pragma unroll
  for (int o = 32; o; o >>= 1) ss += __shfl_xor(ss, o, 64);
  float inv = 1.f / fmaxf(sqrtf(ss), 1e-12f);
  *(float2*)&Y[(size_t)row * kH2 + lane * 2] = make_float2(v.x * inv, v.y * inv);
}

// =========================================================================
extern "C" void kernel_launch(void* const* d_in, const int* in_sizes, int n_in,
                              void* d_out, int out_size, void* d_ws, size_t ws_size,
                              hipStream_t stream)
{
  const float* x        = (const float*)d_in[0];
  const int*   srcI     = (const int*)d_in[1];
  const int*   dstI     = (const int*)d_in[2];
  const float* pos_x    = (const float*)d_in[4];
  const int*   psrc     = (const int*)d_in[5];
  const int*   pdst     = (const int*)d_in[6];
  const float* neg_x    = (const float*)d_in[8];
  const int*   nsrc     = (const int*)d_in[9];
  const int*   ndst     = (const int*)d_in[10];
  const float* target_x = (const float*)d_in[12];
  const float* noise    = (const float*)d_in[13];
  const float* W_enc1   = (const float*)d_in[14];
  const float* b_enc1   = (const float*)d_in[15];
  const float* W_enc2   = (const float*)d_in[16];
  const float* b_enc2   = (const float*)d_in[17];
  const float* W_dec1   = (const float*)d_in[18];
  const float* W_dec2   = (const float*)d_in[19];
  const float* Wn1      = (const float*)d_in[20];
  const float* bn1      = (const float*)d_in[21];
  const float* Wn2      = (const float*)d_in[22];
  const float* bn2      = (const float*)d_in[23];
  const float* Ws1      = (const float*)d_in[24];
  const float* bs1      = (const float*)d_in[25];
  const float* Wp1      = (const float*)d_in[26];
  const float* bp1      = (const float*)d_in[27];
  const float* Wp2      = (const float*)d_in[28];
  const float* bp2      = (const float*)d_in[29];

  float* out  = (float*)d_out;
  float* o_z   = out;                 // N x 128
  float* o_zg  = out + 6400000;       // 500 x 128
  float* o_xr  = out + 6464000;       // N x 128
  float* o_pos = out + 12864000;      // 500 x 128
  float* o_neg = out + 12928000;
  float* o_zgm = out + 12992000;      // o_zgm||o_zpm contiguous 1000 x 128
  float* o_tz  = out + 13120000;

  // WORKSPACE MAP (float offsets; r2-r4 audit per launch):
  //  q0 [0, 6.4M):    hB fp16 N x 256 (enc1 y0 writes, enc2 reads)
  //  q1 [6.4M, ..):   pstat 256000 f32 (enc1 y0 -> bn_red); later t1/t2 (target)
  //  q3 [19.2M, ..):  z16 fp16 N x 128 (enc2 -> dec)
  //  zz ws+22.4M; t1000 ws+22.6M; Wt ws+25.6M; stats ws+25.7M.
  float* ws = (float*)d_ws;
  _Float16* hB  = (_Float16*)ws;
  float* pstat  = ws + 6400000;
  _Float16* z16 = (_Float16*)(ws + 19200000);
  float* zz    = ws + 22400000;
  float* t1000 = ws + 22600000;
  float* t1    = ws + 6400000;        // target-time (pstat dead)
  float* t2    = ws + 6700000;
  _Float16* hWt = (_Float16*)(ws + 25600000);
  float* stats = ws + 25700000;
  if (ws_size < (size_t)(25921024) * sizeof(float)) return;

  _Float16* WtEnc1 = hWt;
  _Float16* WtEnc2 = hWt + 32768;
  _Float16* WtDec1 = hWt + 65536;
  _Float16* WtDec2 = hWt + 98304;
  _Float16* WtS1   = hWt + 131072;

  (void)hipFuncSetAttribute((const void*)enc1_k,
      hipFuncAttributeMaxDynamicSharedMemorySize, kLds1);
  (void)hipFuncSetAttribute((const void*)enc2_k,
      hipFuncAttributeMaxDynamicSharedMemorySize, kLds2);

  auto gg = [](int M, int Nc) {
    return dim3((unsigned)((M + 127) / 128), (unsigned)(Nc / 64), 1);
  };

  // 1. weight prep
  wprep_k<<<640, 256, 0, stream>>>(W_enc1, W_enc2, W_dec1, W_dec2, Ws1, hWt);

  // 2. phase-1 fused encoder: main(y0) -> hB+pstat; pos/neg(y1,2) -> o_pos/o_neg
  enc1_k<<<dim3(kB, 3), 512, kLds1, stream>>>(
      x, pos_x, neg_x, srcI, psrc, nsrc, dstI, pdst, ndst,
      WtEnc1, WtS1, WtEnc2, b_enc1, bs1, b_enc2,
      hB, pstat, o_pos, o_neg);

  // 3. BN finalize
  bn_red_k<<<1, 256, 0, stream>>>(pstat, stats);

  // 4. phase-2 fused encoder (main): hB -> o_z, z16, o_zg, zz
  enc2_k<<<kB, 512, kLds2, stream>>>(
      hB, stats + 512, WtEnc2, b_enc2, srcI, dstI, noise, o_z, z16, o_zg, zz);

  // 5. fused decoder: z16 -> o_xr
  dec_fused_k<<<782, 512, 0, stream>>>(z16, WtDec1, WtDec2, o_xr, kN);

  // 6-7. merged projection heads
  gemm_k<1><<<gg(1000, kH2), 256, 0, stream>>>(zz, Wp1, bp1, t1000, 1000, kH2, kH2);
  gemm_k<0><<<gg(1000, kH2), 256, 0, stream>>>(t1000, Wp2, bp2, o_zgm, 1000, kH2, kH2);

  // 8-11. target node encoder
  gemm_k<1><<<gg(kB, kH1), 256, 0, stream>>>(target_x, Wn1, bn1, t1, kB, kF0, kH1);
  bn_cols_k<<<256, 64, 0, stream>>>(t1, kB, kH1);
  gemm_k<0><<<gg(kB, kH2), 256, 0, stream>>>(t1, Wn2, bn2, t2, kB, kH1, kH2);
  l2n_k<<<125, 256, 0, stream>>>(t2, o_tz, kB);

  (void)in_sizes; (void)n_in; (void)out_size;
}